// Round 1
// baseline (14997.899 us; speedup 1.0000x reference)
//
#include <hip/hip_runtime.h>
#include <hip/hip_bf16.h>
#include <math.h>

// Sizes (compile-time constants for this problem)
#define DD    1024
#define SS    1024
#define BB    4
#define EE    4
#define DFF   4096
#define VOC   32000

// ---------------------------------------------------------------------------
// fp32 tiled GEMM: C[M][N] = A[M][K] * op(B) (+bias, epilogue)
// BMODE 0: B is N x K row-major (C = A B^T)        [Wih, Wfc]
// BMODE 1: B is K x N row-major (C = A B)          [W1, W2] with expert index
// EPI 0: + bias1 (+ bias2 if non-null)
// EPI 1: gelu_exact(x + bias1)
// EPI 2: (x + bias1) * scaleP[blockIdx.z]
// GATHER: A row m comes from A + gidx[m]*K   (embedding fused into GEMM)
// Tiles: 64x64, BK=16, 256 threads, 4x4 per thread.
// ---------------------------------------------------------------------------
template<int BMODE, int EPI, bool GATHER>
__global__ __launch_bounds__(256)
void gemm_f32(const float* __restrict__ A,
              const int*   __restrict__ gidx,
              const float* __restrict__ Bm,
              const float* __restrict__ bias1,
              const float* __restrict__ bias2,
              float*       __restrict__ C,
              int K, int N,
              const float* __restrict__ scaleP,
              const int*   __restrict__ expIdx,
              long long aStride, long long cStride, long long bExpStride)
{
    __shared__ float As[16][68];
    __shared__ float Bs[16][68];

    const int tid = threadIdx.x;
    const int bx = blockIdx.x, by = blockIdx.y, bz = blockIdx.z;

    const float* Ab = A + (long long)bz * aStride;
    float*       Cb = C + (long long)bz * cStride;
    const float* Bb = Bm;
    const float* b1 = bias1;
    if constexpr (BMODE == 1) {
        int e = expIdx[bz];
        Bb += (long long)e * bExpStride;
        b1 += (long long)e * N;
    }

    const int r  = tid >> 2;           // 0..63   (A / B-BT row within tile)
    const int c4 = (tid & 3) * 4;      // k offset for A / B-BT loads
    const int kk = tid >> 4;           // 0..15   (B-NN k row)
    const int n4 = (tid & 15) * 4;     // B-NN col offset
    const int tx = tid & 15, ty = tid >> 4;

    const float* arow;
    if constexpr (GATHER)
        arow = A + (long long)gidx[by * 64 + r] * K + c4;
    else
        arow = Ab + (long long)(by * 64 + r) * K + c4;

    const float* brow_bt = Bb + (long long)(bx * 64 + r) * K + c4;
    const float* brow_nn = Bb + (long long)kk * N + bx * 64 + n4;

    float acc[4][4] = {};

    for (int k0 = 0; k0 < K; k0 += 16) {
        float4 av = *(const float4*)(arow + k0);
        As[c4 + 0][r] = av.x; As[c4 + 1][r] = av.y;
        As[c4 + 2][r] = av.z; As[c4 + 3][r] = av.w;
        if constexpr (BMODE == 0) {
            float4 bv = *(const float4*)(brow_bt + k0);
            Bs[c4 + 0][r] = bv.x; Bs[c4 + 1][r] = bv.y;
            Bs[c4 + 2][r] = bv.z; Bs[c4 + 3][r] = bv.w;
        } else {
            float4 bv = *(const float4*)(brow_nn + (long long)k0 * N);
            *(float4*)&Bs[kk][n4] = bv;
        }
        __syncthreads();
        #pragma unroll
        for (int k2 = 0; k2 < 16; ++k2) {
            float4 a = *(const float4*)&As[k2][ty * 4];
            float4 b = *(const float4*)&Bs[k2][tx * 4];
            acc[0][0] += a.x * b.x; acc[0][1] += a.x * b.y; acc[0][2] += a.x * b.z; acc[0][3] += a.x * b.w;
            acc[1][0] += a.y * b.x; acc[1][1] += a.y * b.y; acc[1][2] += a.y * b.z; acc[1][3] += a.y * b.w;
            acc[2][0] += a.z * b.x; acc[2][1] += a.z * b.y; acc[2][2] += a.z * b.z; acc[2][3] += a.z * b.w;
            acc[3][0] += a.w * b.x; acc[3][1] += a.w * b.y; acc[3][2] += a.w * b.z; acc[3][3] += a.w * b.w;
        }
        __syncthreads();
    }

    const float scale = (EPI == 2) ? scaleP[bz] : 1.0f;
    const int row0 = by * 64 + ty * 4;
    const int col0 = bx * 64 + tx * 4;
    const bool hb2 = (bias2 != nullptr);
    #pragma unroll
    for (int i = 0; i < 4; ++i) {
        float o[4];
        #pragma unroll
        for (int j = 0; j < 4; ++j) {
            int col = col0 + j;
            float v = acc[i][j] + b1[col];
            if (hb2) v += bias2[col];
            if constexpr (EPI == 1)
                v = 0.5f * v * (1.0f + erff(v * 0.70710678118654752440f));
            if constexpr (EPI == 2)
                v *= scale;
            o[j] = v;
        }
        *(float4*)(Cb + (long long)(row0 + i) * N + col0) =
            make_float4(o[0], o[1], o[2], o[3]);
    }
}

// ---------------------------------------------------------------------------
// Persistent RNN: h_t = tanh(U_t + h_{t-1} @ Whh^T), stores all h_t to HS.
// 64 blocks x 256 threads. Block g owns output dims [16g, 16g+16).
// Thread (kq=tid>>4, dl=tid&15): Whh[g*16+dl][kq*64 .. +64) held in registers.
// h exchanged via global double buffer + device-scope monotonic barrier.
// ---------------------------------------------------------------------------
__global__ __launch_bounds__(256)
void rnn_kernel(const float* __restrict__ U,
                const float* __restrict__ Whh,
                float*       __restrict__ HS,
                float*       __restrict__ hbuf,     // 2 * (4*1024) floats
                unsigned*    __restrict__ bar)
{
    __shared__ float hs_s[4][1084];       // skewed: idx = k + ((k>>6)<<2)
    __shared__ float red_s[4][4][16];     // [wave][b][dl]

    const int tid = threadIdx.x;
    const int g = blockIdx.x;
    const int kq = tid >> 4, dl = tid & 15;
    const int d_own = g * 16 + dl;
    const int wv = tid >> 6;
    const int lane = tid & 63;

    float4 wreg[16];
    #pragma unroll
    for (int j4 = 0; j4 < 16; ++j4)
        wreg[j4] = *(const float4*)(Whh + (long long)d_own * DD + kq * 64 + j4 * 4);

    for (int t = 0; t < SS; ++t) {
        const float* hb_cur = hbuf + (t & 1) * (BB * DD);
        float*       hb_nxt = hbuf + ((t + 1) & 1) * (BB * DD);

        // stage h (4x1024 = 16KB) into skewed LDS
        #pragma unroll
        for (int i = 0; i < 4; ++i) {
            int idx4 = tid + i * 256;           // float4 index 0..1023
            int b = idx4 >> 8, k = (idx4 & 255) * 4;
            float4 hv = *(const float4*)(hb_cur + b * DD + k);
            *(float4*)&hs_s[b][k + ((k >> 6) << 2)] = hv;
        }
        __syncthreads();

        float acc0 = 0.f, acc1 = 0.f, acc2 = 0.f, acc3 = 0.f;
        const int hbase = kq * 68;   // kq*64 + skew kq*4
        #pragma unroll
        for (int j4 = 0; j4 < 16; ++j4) {
            float4 w4 = wreg[j4];
            float4 h0 = *(const float4*)&hs_s[0][hbase + j4 * 4];
            float4 h1 = *(const float4*)&hs_s[1][hbase + j4 * 4];
            float4 h2 = *(const float4*)&hs_s[2][hbase + j4 * 4];
            float4 h3 = *(const float4*)&hs_s[3][hbase + j4 * 4];
            acc0 += w4.x * h0.x + w4.y * h0.y + w4.z * h0.z + w4.w * h0.w;
            acc1 += w4.x * h1.x + w4.y * h1.y + w4.z * h1.z + w4.w * h1.w;
            acc2 += w4.x * h2.x + w4.y * h2.y + w4.z * h2.z + w4.w * h2.w;
            acc3 += w4.x * h3.x + w4.y * h3.y + w4.z * h3.z + w4.w * h3.w;
        }
        // reduce over kq&3 (lane bits 4..5)
        acc0 += __shfl_xor(acc0, 16); acc0 += __shfl_xor(acc0, 32);
        acc1 += __shfl_xor(acc1, 16); acc1 += __shfl_xor(acc1, 32);
        acc2 += __shfl_xor(acc2, 16); acc2 += __shfl_xor(acc2, 32);
        acc3 += __shfl_xor(acc3, 16); acc3 += __shfl_xor(acc3, 32);
        if ((lane >> 4) == 0) {
            red_s[wv][0][dl] = acc0; red_s[wv][1][dl] = acc1;
            red_s[wv][2][dl] = acc2; red_s[wv][3][dl] = acc3;
        }
        __syncthreads();
        if (tid < 64) {
            int b = tid >> 4, d2 = tid & 15;
            float tot = red_s[0][b][d2] + red_s[1][b][d2] +
                        red_s[2][b][d2] + red_s[3][b][d2];
            int d = g * 16 + d2;
            long long mrow = (long long)(b * SS + t) * DD;
            float h = tanhf(U[mrow + d] + tot);
            hb_nxt[b * DD + d] = h;
            HS[mrow + d] = h;
        }
        __threadfence();          // agent-scope release of this step's h writes
        __syncthreads();
        if (tid == 0) {
            __hip_atomic_fetch_add(bar, 1u, __ATOMIC_RELEASE, __HIP_MEMORY_SCOPE_AGENT);
            unsigned target = 64u * (unsigned)(t + 1);
            while (__hip_atomic_load(bar, __ATOMIC_ACQUIRE, __HIP_MEMORY_SCOPE_AGENT) < target) {
                __builtin_amdgcn_s_sleep(2);
            }
        }
        __syncthreads();
    }
}

// mean over s: MEANX[b][d] = (1/S) sum_s HS[b,s,d].  grid = 64 (b*16 + dchunk)
__global__ __launch_bounds__(256)
void mean_kernel(const float* __restrict__ HS, float* __restrict__ MEANX)
{
    __shared__ float red[4][64];
    const int b = blockIdx.x >> 4, dc = blockIdx.x & 15;
    const int jd = threadIdx.x & 63, sq = threadIdx.x >> 6;
    float acc = 0.f;
    const float* base = HS + (long long)b * SS * DD + dc * 64 + jd;
    for (int s = sq * 256; s < sq * 256 + 256; ++s)
        acc += base[(long long)s * DD];
    red[sq][jd] = acc;
    __syncthreads();
    if (threadIdx.x < 64) {
        float m = red[0][threadIdx.x] + red[1][threadIdx.x] +
                  red[2][threadIdx.x] + red[3][threadIdx.x];
        MEANX[b * DD + dc * 64 + threadIdx.x] = m * (1.0f / (float)SS);
    }
}

// gates = softmax(MEANX @ Wg^T); top-1 weight + index per batch. 1 block.
__global__ __launch_bounds__(256)
void gate_kernel(const float* __restrict__ MEANX, const float* __restrict__ Wg,
                 float* __restrict__ WGATE, int* __restrict__ IDX)
{
    __shared__ float sc[4][4];
    const int tid = threadIdx.x;
    const int p = tid >> 4, l = tid & 15;
    const int b = p >> 2, e = p & 3;
    float acc = 0.f;
    for (int j = 0; j < 64; ++j)
        acc += MEANX[b * DD + l * 64 + j] * Wg[e * DD + l * 64 + j];
    acc += __shfl_xor(acc, 1); acc += __shfl_xor(acc, 2);
    acc += __shfl_xor(acc, 4); acc += __shfl_xor(acc, 8);
    if (l == 0) sc[b][e] = acc;
    __syncthreads();
    if (tid < 4) {
        float s0 = sc[tid][0], s1 = sc[tid][1], s2 = sc[tid][2], s3 = sc[tid][3];
        float mx = fmaxf(fmaxf(s0, s1), fmaxf(s2, s3));
        float e0 = expf(s0 - mx), e1 = expf(s1 - mx);
        float e2 = expf(s2 - mx), e3 = expf(s3 - mx);
        float inv = 1.0f / (e0 + e1 + e2 + e3);
        float pr[4] = {e0 * inv, e1 * inv, e2 * inv, e3 * inv};
        int arg = 0; float best = pr[0];
        if (pr[1] > best) { best = pr[1]; arg = 1; }
        if (pr[2] > best) { best = pr[2]; arg = 2; }
        if (pr[3] > best) { best = pr[3]; arg = 3; }
        WGATE[tid] = best;
        IDX[tid] = arg;
    }
}

// ---------------------------------------------------------------------------
extern "C" void kernel_launch(void* const* d_in, const int* in_sizes, int n_in,
                              void* d_out, int out_size, void* d_ws, size_t ws_size,
                              hipStream_t stream)
{
    const int*   tokens = (const int*)  d_in[0];
    const float* emb    = (const float*)d_in[1];
    const float* Wih    = (const float*)d_in[2];
    const float* bih    = (const float*)d_in[3];
    const float* Whh    = (const float*)d_in[4];
    const float* bhh    = (const float*)d_in[5];
    const float* Wg     = (const float*)d_in[6];
    const float* W1     = (const float*)d_in[7];
    const float* b1     = (const float*)d_in[8];
    const float* W2     = (const float*)d_in[9];
    const float* b2     = (const float*)d_in[10];
    const float* Wfc    = (const float*)d_in[11];
    const float* bfc    = (const float*)d_in[12];
    float* out = (float*)d_out;
    float* ws  = (float*)d_ws;

    // ws layout (float offsets)
    float* U     = ws;                       // 4096*1024
    float* HS    = ws + 4194304;             // 4096*1024
    float* H1    = ws + 8388608;             // 4*1024*4096
    float* Y     = ws + 25165824;            // 4096*1024
    float* HBUF  = ws + 29360128;            // 2*4096
    float* MEANX = ws + 29368320;            // 4096
    float* WGATE = ws + 29372416;            // 4
    int*   IDX   = (int*)(ws + 29372424);    // 4 ints
    unsigned* BAR = (unsigned*)(ws + 29372432);

    // deterministic per-launch init (graph-capture safe)
    hipMemsetAsync(HBUF, 0, BB * DD * sizeof(float), stream);   // h0 = 0
    hipMemsetAsync(BAR, 0, sizeof(unsigned), stream);

    // U = emb[tokens] @ Wih^T + bih + bhh
    gemm_f32<0, 0, true><<<dim3(DD / 64, (BB * SS) / 64, 1), 256, 0, stream>>>(
        emb, tokens, Wih, bih, bhh, U, DD, DD, nullptr, nullptr, 0, 0, 0);

    // RNN scan
    rnn_kernel<<<64, 256, 0, stream>>>(U, Whh, HS, HBUF, BAR);

    // gate
    mean_kernel<<<64, 256, 0, stream>>>(HS, MEANX);
    gate_kernel<<<1, 256, 0, stream>>>(MEANX, Wg, WGATE, IDX);

    // H1 = gelu(HS @ W1[idx] + b1[idx])
    gemm_f32<1, 1, false><<<dim3(DFF / 64, SS / 64, BB), 256, 0, stream>>>(
        HS, nullptr, W1, b1, nullptr, H1, DD, DFF, nullptr, IDX,
        (long long)SS * DD, (long long)SS * DFF, (long long)DD * DFF);

    // Y = (H1 @ W2[idx] + b2[idx]) * w
    gemm_f32<1, 2, false><<<dim3(DD / 64, SS / 64, BB), 256, 0, stream>>>(
        H1, nullptr, W2, b2, nullptr, Y, DFF, DD, WGATE, IDX,
        (long long)SS * DFF, (long long)SS * DD, (long long)DFF * DD);

    // logits = Y @ Wfc^T + bfc
    gemm_f32<0, 0, false><<<dim3(VOC / 64, (BB * SS) / 64, 1), 256, 0, stream>>>(
        Y, nullptr, Wfc, bfc, nullptr, out, DD, VOC, nullptr, nullptr, 0, 0, 0);
}

// Round 2
// 5434.852 us; speedup vs baseline: 2.7596x; 2.7596x over previous
//
#include <hip/hip_runtime.h>
#include <hip/hip_bf16.h>
#include <math.h>

// Sizes (compile-time constants for this problem)
#define DD    1024
#define SS    1024
#define BB    4
#define EE    4
#define DFF   4096
#define VOC   32000

typedef __attribute__((ext_vector_type(8))) short v8s;   // 8 bf16 (4 VGPRs)
typedef __attribute__((ext_vector_type(4))) float v4f;   // MFMA accumulator

// ---------------------------------------------------------------------------
// fp32 tiled GEMM (unchanged from R1): C[M][N] = A[M][K] * op(B) (+bias, epi)
// BMODE 0: B is N x K row-major (C = A B^T)        [Wih]
// BMODE 1: B is K x N row-major (C = A B)          [W1, W2] with expert index
// EPI 0: + bias1 (+ bias2 if non-null) | EPI 1: gelu | EPI 2: *scaleP[bz]
// ---------------------------------------------------------------------------
template<int BMODE, int EPI, bool GATHER>
__global__ __launch_bounds__(256)
void gemm_f32(const float* __restrict__ A,
              const int*   __restrict__ gidx,
              const float* __restrict__ Bm,
              const float* __restrict__ bias1,
              const float* __restrict__ bias2,
              float*       __restrict__ C,
              int K, int N,
              const float* __restrict__ scaleP,
              const int*   __restrict__ expIdx,
              long long aStride, long long cStride, long long bExpStride)
{
    __shared__ float As[16][68];
    __shared__ float Bs[16][68];

    const int tid = threadIdx.x;
    const int bx = blockIdx.x, by = blockIdx.y, bz = blockIdx.z;

    const float* Ab = A + (long long)bz * aStride;
    float*       Cb = C + (long long)bz * cStride;
    const float* Bb = Bm;
    const float* b1 = bias1;
    if constexpr (BMODE == 1) {
        int e = expIdx[bz];
        Bb += (long long)e * bExpStride;
        b1 += (long long)e * N;
    }

    const int r  = tid >> 2;
    const int c4 = (tid & 3) * 4;
    const int kk = tid >> 4;
    const int n4 = (tid & 15) * 4;
    const int tx = tid & 15, ty = tid >> 4;

    const float* arow;
    if constexpr (GATHER)
        arow = A + (long long)gidx[by * 64 + r] * K + c4;
    else
        arow = Ab + (long long)(by * 64 + r) * K + c4;

    const float* brow_bt = Bb + (long long)(bx * 64 + r) * K + c4;
    const float* brow_nn = Bb + (long long)kk * N + bx * 64 + n4;

    float acc[4][4] = {};

    for (int k0 = 0; k0 < K; k0 += 16) {
        float4 av = *(const float4*)(arow + k0);
        As[c4 + 0][r] = av.x; As[c4 + 1][r] = av.y;
        As[c4 + 2][r] = av.z; As[c4 + 3][r] = av.w;
        if constexpr (BMODE == 0) {
            float4 bv = *(const float4*)(brow_bt + k0);
            Bs[c4 + 0][r] = bv.x; Bs[c4 + 1][r] = bv.y;
            Bs[c4 + 2][r] = bv.z; Bs[c4 + 3][r] = bv.w;
        } else {
            float4 bv = *(const float4*)(brow_nn + (long long)k0 * N);
            *(float4*)&Bs[kk][n4] = bv;
        }
        __syncthreads();
        #pragma unroll
        for (int k2 = 0; k2 < 16; ++k2) {
            float4 a = *(const float4*)&As[k2][ty * 4];
            float4 b = *(const float4*)&Bs[k2][tx * 4];
            acc[0][0] += a.x * b.x; acc[0][1] += a.x * b.y; acc[0][2] += a.x * b.z; acc[0][3] += a.x * b.w;
            acc[1][0] += a.y * b.x; acc[1][1] += a.y * b.y; acc[1][2] += a.y * b.z; acc[1][3] += a.y * b.w;
            acc[2][0] += a.z * b.x; acc[2][1] += a.z * b.y; acc[2][2] += a.z * b.z; acc[2][3] += a.z * b.w;
            acc[3][0] += a.w * b.x; acc[3][1] += a.w * b.y; acc[3][2] += a.w * b.z; acc[3][3] += a.w * b.w;
        }
        __syncthreads();
    }

    const float scale = (EPI == 2) ? scaleP[bz] : 1.0f;
    const int row0 = by * 64 + ty * 4;
    const int col0 = bx * 64 + tx * 4;
    const bool hb2 = (bias2 != nullptr);
    #pragma unroll
    for (int i = 0; i < 4; ++i) {
        float o[4];
        #pragma unroll
        for (int j = 0; j < 4; ++j) {
            int col = col0 + j;
            float v = acc[i][j] + b1[col];
            if (hb2) v += bias2[col];
            if constexpr (EPI == 1)
                v = 0.5f * v * (1.0f + erff(v * 0.70710678118654752440f));
            if constexpr (EPI == 2)
                v *= scale;
            o[j] = v;
        }
        *(float4*)(Cb + (long long)(row0 + i) * N + col0) =
            make_float4(o[0], o[1], o[2], o[3]);
    }
}

// ---------------------------------------------------------------------------
// Persistent RNN v2: flag-broadcast sync through the coherence point.
// 64 blocks x 256 threads; block g owns output dims [16g, 16g+16).
// h_t published directly into HS via relaxed AGENT atomics (sc1 write-through,
// visible at IF, no fences). One flag per (step, block), 64B apart; 64 threads
// poll the 64 flags in parallel. Plain loads for h are safe: the lines were
// never cached before all flags confirmed (flag-all-before-any-read).
// ---------------------------------------------------------------------------
__global__ __launch_bounds__(256)
void rnn_kernel(const float* __restrict__ U,
                const float* __restrict__ Whh,
                float*       __restrict__ HS,
                unsigned*    __restrict__ flags)   // [SS][64] stride-16 u32
{
    __shared__ float hs_s[4][1084];       // skewed: idx = k + ((k>>6)<<2)
    __shared__ float red_s[4][4][16];     // [wave][b][dl]

    const int tid = threadIdx.x;
    const int g = blockIdx.x;
    const int kq = tid >> 4, dl = tid & 15;
    const int d_own = g * 16 + dl;
    const int wv = tid >> 6;
    const int lane = tid & 63;

    float4 wreg[16];
    #pragma unroll
    for (int j4 = 0; j4 < 16; ++j4)
        wreg[j4] = *(const float4*)(Whh + (long long)d_own * DD + kq * 64 + j4 * 4);

    for (int t = 0; t < SS; ++t) {
        // prefetch this step's U value early (independent of the exchange)
        float u_pre = 0.f;
        if (tid < 64) {
            int b = tid >> 4, d2 = tid & 15;
            u_pre = U[((size_t)(b * SS + t)) * DD + g * 16 + d2];
        }

        if (t > 0) {
            // 1) wait for ALL 64 producer flags of step t-1 (parallel pollers)
            if (tid < 64) {
                const unsigned* fp = flags + (size_t)(t - 1) * 1024 + tid * 16;
                while (__hip_atomic_load(fp, __ATOMIC_RELAXED,
                                         __HIP_MEMORY_SCOPE_AGENT) == 0u)
                    __builtin_amdgcn_s_sleep(1);
            }
            __syncthreads();
            // 2) stage h_{t-1} (16 KB) into skewed LDS with plain float4 loads
            #pragma unroll
            for (int i = 0; i < 4; ++i) {
                int idx4 = tid + i * 256;
                int b = idx4 >> 8, k = (idx4 & 255) * 4;
                float4 hv = *(const float4*)(HS + ((size_t)(b * SS + (t - 1))) * DD + k);
                *(float4*)&hs_s[b][k + ((k >> 6) << 2)] = hv;
            }
            __syncthreads();
            // 3) matvec slice
            float acc0 = 0.f, acc1 = 0.f, acc2 = 0.f, acc3 = 0.f;
            const int hbase = kq * 68;
            #pragma unroll
            for (int j4 = 0; j4 < 16; ++j4) {
                float4 w4 = wreg[j4];
                float4 h0 = *(const float4*)&hs_s[0][hbase + j4 * 4];
                float4 h1 = *(const float4*)&hs_s[1][hbase + j4 * 4];
                float4 h2 = *(const float4*)&hs_s[2][hbase + j4 * 4];
                float4 h3 = *(const float4*)&hs_s[3][hbase + j4 * 4];
                acc0 += w4.x * h0.x + w4.y * h0.y + w4.z * h0.z + w4.w * h0.w;
                acc1 += w4.x * h1.x + w4.y * h1.y + w4.z * h1.z + w4.w * h1.w;
                acc2 += w4.x * h2.x + w4.y * h2.y + w4.z * h2.z + w4.w * h2.w;
                acc3 += w4.x * h3.x + w4.y * h3.y + w4.z * h3.z + w4.w * h3.w;
            }
            acc0 += __shfl_xor(acc0, 16); acc0 += __shfl_xor(acc0, 32);
            acc1 += __shfl_xor(acc1, 16); acc1 += __shfl_xor(acc1, 32);
            acc2 += __shfl_xor(acc2, 16); acc2 += __shfl_xor(acc2, 32);
            acc3 += __shfl_xor(acc3, 16); acc3 += __shfl_xor(acc3, 32);
            if ((lane >> 4) == 0) {
                red_s[wv][0][dl] = acc0; red_s[wv][1][dl] = acc1;
                red_s[wv][2][dl] = acc2; red_s[wv][3][dl] = acc3;
            }
            __syncthreads();
        }

        // 4) finalize own 64 outputs, publish via agent-coherent stores
        if (tid < 64) {
            int b = tid >> 4, d2 = tid & 15;
            float tot = 0.f;
            if (t > 0)
                tot = red_s[0][b][d2] + red_s[1][b][d2] +
                      red_s[2][b][d2] + red_s[3][b][d2];
            int d = g * 16 + d2;
            size_t mrow = ((size_t)(b * SS + t)) * DD;
            float h = tanhf(u_pre + tot);
            __hip_atomic_store(HS + mrow + d, h, __ATOMIC_RELAXED,
                               __HIP_MEMORY_SCOPE_AGENT);
        }
        // hand-rolled release: stores above are write-through coherent, so a
        // vmcnt drain (wave 0 only owns tids 0..63) makes them globally
        // visible; then set this block's flag for step t.
        if (tid < 64)
            asm volatile("s_waitcnt vmcnt(0)" ::: "memory");
        if (tid == 0)
            __hip_atomic_store(flags + (size_t)t * 1024 + g * 16, 1u,
                               __ATOMIC_RELAXED, __HIP_MEMORY_SCOPE_AGENT);
        __syncthreads();   // protect hs_s / red_s reuse next step
    }
}

// mean over s: MEANX[b][d] = (1/S) sum_s HS[b,s,d].  grid = 64
__global__ __launch_bounds__(256)
void mean_kernel(const float* __restrict__ HS, float* __restrict__ MEANX)
{
    __shared__ float red[4][64];
    const int b = blockIdx.x >> 4, dc = blockIdx.x & 15;
    const int jd = threadIdx.x & 63, sq = threadIdx.x >> 6;
    float acc = 0.f;
    const float* base = HS + (long long)b * SS * DD + dc * 64 + jd;
    for (int s = sq * 256; s < sq * 256 + 256; ++s)
        acc += base[(long long)s * DD];
    red[sq][jd] = acc;
    __syncthreads();
    if (threadIdx.x < 64) {
        float m = red[0][threadIdx.x] + red[1][threadIdx.x] +
                  red[2][threadIdx.x] + red[3][threadIdx.x];
        MEANX[b * DD + dc * 64 + threadIdx.x] = m * (1.0f / (float)SS);
    }
}

// gates = softmax(MEANX @ Wg^T); top-1 weight + index per batch. 1 block.
__global__ __launch_bounds__(256)
void gate_kernel(const float* __restrict__ MEANX, const float* __restrict__ Wg,
                 float* __restrict__ WGATE, int* __restrict__ IDX)
{
    __shared__ float sc[4][4];
    const int tid = threadIdx.x;
    const int p = tid >> 4, l = tid & 15;
    const int b = p >> 2, e = p & 3;
    float acc = 0.f;
    for (int j = 0; j < 64; ++j)
        acc += MEANX[b * DD + l * 64 + j] * Wg[e * DD + l * 64 + j];
    acc += __shfl_xor(acc, 1); acc += __shfl_xor(acc, 2);
    acc += __shfl_xor(acc, 4); acc += __shfl_xor(acc, 8);
    if (l == 0) sc[b][e] = acc;
    __syncthreads();
    if (tid < 4) {
        float s0 = sc[tid][0], s1 = sc[tid][1], s2 = sc[tid][2], s3 = sc[tid][3];
        float mx = fmaxf(fmaxf(s0, s1), fmaxf(s2, s3));
        float e0 = expf(s0 - mx), e1 = expf(s1 - mx);
        float e2 = expf(s2 - mx), e3 = expf(s3 - mx);
        float inv = 1.0f / (e0 + e1 + e2 + e3);
        float pr[4] = {e0 * inv, e1 * inv, e2 * inv, e3 * inv};
        int arg = 0; float best = pr[0];
        if (pr[1] > best) { best = pr[1]; arg = 1; }
        if (pr[2] > best) { best = pr[2]; arg = 2; }
        if (pr[3] > best) { best = pr[3]; arg = 3; }
        WGATE[tid] = best;
        IDX[tid] = arg;
    }
}

// fp32 -> bf16 (RNE) cast, float4-granular, grid-stride
__device__ __forceinline__ unsigned short f2b(float f) {
    unsigned u = __float_as_uint(f);
    unsigned r = (u + 0x7FFFu + ((u >> 16) & 1u)) >> 16;
    return (unsigned short)r;
}
__global__ __launch_bounds__(256)
void cast_kernel(const float* __restrict__ in, unsigned short* __restrict__ out,
                 long long n4)
{
    long long stride = (long long)gridDim.x * blockDim.x;
    for (long long i = (long long)blockIdx.x * blockDim.x + threadIdx.x;
         i < n4; i += stride) {
        float4 v = ((const float4*)in)[i];
        ushort4 o;
        o.x = f2b(v.x); o.y = f2b(v.y); o.z = f2b(v.z); o.w = f2b(v.w);
        ((ushort4*)out)[i] = o;
    }
}

// ---------------------------------------------------------------------------
// bf16 MFMA GEMM (m97 structure): C[M][N] = A[M][K] @ Bt[N][K]^T + bias
// 128x128 tile, BK=32, 256 threads (4 waves, 2x2 wave grid, 64x64 per wave),
// global_load_lds width 16, mfma_f32_16x16x32_bf16.
// A-frag: lane l holds A[l&15][(l>>4)*8 + j]; B-frag: Bt row n = l&15, same k.
// C/D: col = lane&15, row = (lane>>4)*4 + reg.
// ---------------------------------------------------------------------------
__device__ __forceinline__ void load_lds16(const void* g, void* l) {
    __builtin_amdgcn_global_load_lds(
        (const __attribute__((address_space(1))) unsigned int*)g,
        (__attribute__((address_space(3))) unsigned int*)l, 16, 0, 0);
}

__global__ __launch_bounds__(256)
void gemm_bf16_bt(const unsigned short* __restrict__ A,   // M x K bf16
                  const unsigned short* __restrict__ Bt,  // N x K bf16
                  const float* __restrict__ bias,         // [N]
                  float* __restrict__ C, int N, int K)
{
    __shared__ __align__(16) unsigned short Asm[128 * 32];
    __shared__ __align__(16) unsigned short Bsm[128 * 32];

    const int tid = threadIdx.x;
    const int wave = tid >> 6, lane = tid & 63;
    const int bm = blockIdx.y * 128, bn = blockIdx.x * 128;
    const int wm = (wave >> 1) * 64, wn = (wave & 1) * 64;
    const int fr = lane & 15, kh = lane >> 4;

    // staging source rows for the two 4KB chunks this wave covers
    const int lo0 = wave * 1024 + lane * 16;       // byte offset, chunk 0
    const int lo1 = 4096 + lo0;                    // chunk 1
    const int r0 = lo0 >> 6, q0 = (lo0 & 63) >> 1;
    const int r1 = lo1 >> 6, q1 = (lo1 & 63) >> 1;
    const unsigned short* a0 = A  + (size_t)(bm + r0) * K + q0;
    const unsigned short* a1 = A  + (size_t)(bm + r1) * K + q1;
    const unsigned short* b0 = Bt + (size_t)(bn + r0) * K + q0;
    const unsigned short* b1 = Bt + (size_t)(bn + r1) * K + q1;

    v4f acc[4][4];
    #pragma unroll
    for (int i = 0; i < 4; ++i)
        #pragma unroll
        for (int j = 0; j < 4; ++j) {
            acc[i][j][0] = 0.f; acc[i][j][1] = 0.f;
            acc[i][j][2] = 0.f; acc[i][j][3] = 0.f;
        }

    for (int k0 = 0; k0 < K; k0 += 32) {
        load_lds16(a0 + k0, (char*)Asm + wave * 1024);
        load_lds16(a1 + k0, (char*)Asm + 4096 + wave * 1024);
        load_lds16(b0 + k0, (char*)Bsm + wave * 1024);
        load_lds16(b1 + k0, (char*)Bsm + 4096 + wave * 1024);
        __syncthreads();

        v8s af[4], bfv[4];
        #pragma unroll
        for (int f = 0; f < 4; ++f) {
            af[f]  = *(const v8s*)((const char*)Asm + ((wm + f * 16 + fr) << 6) + (kh << 4));
            bfv[f] = *(const v8s*)((const char*)Bsm + ((wn + f * 16 + fr) << 6) + (kh << 4));
        }
        #pragma unroll
        for (int fi = 0; fi < 4; ++fi)
            #pragma unroll
            for (int fj = 0; fj < 4; ++fj)
                acc[fi][fj] = __builtin_amdgcn_mfma_f32_16x16x32_bf16(
                    af[fi], bfv[fj], acc[fi][fj], 0, 0, 0);
        __syncthreads();
    }

    #pragma unroll
    for (int fi = 0; fi < 4; ++fi) {
        #pragma unroll
        for (int fj = 0; fj < 4; ++fj) {
            v4f t = acc[fi][fj];
            int col = bn + wn + fj * 16 + fr;
            float bb = bias[col];
            int rbase = bm + wm + fi * 16 + (kh << 2);
            #pragma unroll
            for (int r = 0; r < 4; ++r)
                C[(size_t)(rbase + r) * N + col] = t[r] + bb;
        }
    }
}

// ---------------------------------------------------------------------------
extern "C" void kernel_launch(void* const* d_in, const int* in_sizes, int n_in,
                              void* d_out, int out_size, void* d_ws, size_t ws_size,
                              hipStream_t stream)
{
    const int*   tokens = (const int*)  d_in[0];
    const float* emb    = (const float*)d_in[1];
    const float* Wih    = (const float*)d_in[2];
    const float* bih    = (const float*)d_in[3];
    const float* Whh    = (const float*)d_in[4];
    const float* bhh    = (const float*)d_in[5];
    const float* Wg     = (const float*)d_in[6];
    const float* W1     = (const float*)d_in[7];
    const float* b1     = (const float*)d_in[8];
    const float* W2     = (const float*)d_in[9];
    const float* b2     = (const float*)d_in[10];
    const float* Wfc    = (const float*)d_in[11];
    const float* bfc    = (const float*)d_in[12];
    float* out = (float*)d_out;
    float* ws  = (float*)d_ws;

    // ws layout (float offsets), 117.45 MB total
    float* U     = ws;                       // 4096*1024
    float* HS    = ws + 4194304;             // 4096*1024
    float* H1    = ws + 8388608;             // 4*1024*4096 (64 MB)
    float* Y     = ws + 25165824;            // 4096*1024
    float* MEANX = ws + 29360128;            // 4096
    float* WGATE = ws + 29364224;            // 4
    int*   IDX   = (int*)(ws + 29364228);    // 4 ints
    // aliases (lifetimes disjoint in stream order):
    unsigned*       FLAGS = (unsigned*)H1;        // [1024][64] stride-16 u32, 4 MB; dead after rnn
    unsigned short* Ybf   = (unsigned short*)HS;  // 8.4 MB; written after HS last read
    unsigned short* Wfcbf = (unsigned short*)H1;  // 65.5 MB; written after H1 last read

    hipMemsetAsync(FLAGS, 0, (size_t)SS * 64 * 16 * sizeof(unsigned), stream);

    // U = emb[tokens] @ Wih^T + bih + bhh
    gemm_f32<0, 0, true><<<dim3(DD / 64, (BB * SS) / 64, 1), 256, 0, stream>>>(
        emb, tokens, Wih, bih, bhh, U, DD, DD, nullptr, nullptr, 0, 0, 0);

    // RNN scan (flag-broadcast sync)
    rnn_kernel<<<64, 256, 0, stream>>>(U, Whh, HS, FLAGS);

    // gate
    mean_kernel<<<64, 256, 0, stream>>>(HS, MEANX);
    gate_kernel<<<1, 256, 0, stream>>>(MEANX, Wg, WGATE, IDX);

    // H1 = gelu(HS @ W1[idx] + b1[idx])   (clobbers FLAGS region: rnn is done)
    gemm_f32<1, 1, false><<<dim3(DFF / 64, SS / 64, BB), 256, 0, stream>>>(
        HS, nullptr, W1, b1, nullptr, H1, DD, DFF, nullptr, IDX,
        (long long)SS * DD, (long long)SS * DFF, (long long)DD * DFF);

    // Y = (H1 @ W2[idx] + b2[idx]) * w
    gemm_f32<1, 2, false><<<dim3(DD / 64, SS / 64, BB), 256, 0, stream>>>(
        H1, nullptr, W2, b2, nullptr, Y, DFF, DD, WGATE, IDX,
        (long long)SS * DFF, (long long)SS * DD, (long long)DFF * DD);

    // casts for the bf16 logits GEMM
    cast_kernel<<<1024, 256, 0, stream>>>(Y, Ybf, (long long)(BB * SS) * DD / 4);
    cast_kernel<<<4096, 256, 0, stream>>>(Wfc, Wfcbf, (long long)VOC * DD / 4);

    // logits = Ybf @ Wfcbf^T + bfc   (bf16 MFMA)
    gemm_bf16_bt<<<dim3(VOC / 128, (BB * SS) / 128, 1), 256, 0, stream>>>(
        Ybf, Wfcbf, bfc, out, VOC, DD);
}

// Round 3
// 4542.043 us; speedup vs baseline: 3.3020x; 1.1966x over previous
//
#include <hip/hip_runtime.h>
#include <hip/hip_bf16.h>
#include <math.h>

#define DD    1024
#define SS    1024
#define BB    4
#define EE    4
#define DFF   4096
#define VOC   32000

typedef __attribute__((ext_vector_type(8))) short v8s;   // 8 bf16 (4 VGPRs)
typedef __attribute__((ext_vector_type(4))) float v4f;   // MFMA accumulator

// fp32 -> bf16 (RNE)
__device__ __forceinline__ unsigned short f2b(float f) {
    unsigned u = __float_as_uint(f);
    unsigned r = (u + 0x7FFFu + ((u >> 16) & 1u)) >> 16;
    return (unsigned short)r;
}

// ---------------------------------------------------------------------------
// fp32 tiled GEMM (only used for U = emb[tok] @ Wih^T + bih + bhh now).
// ---------------------------------------------------------------------------
template<int BMODE, int EPI, bool GATHER>
__global__ __launch_bounds__(256)
void gemm_f32(const float* __restrict__ A,
              const int*   __restrict__ gidx,
              const float* __restrict__ Bm,
              const float* __restrict__ bias1,
              const float* __restrict__ bias2,
              float*       __restrict__ C,
              int K, int N)
{
    __shared__ float As[16][68];
    __shared__ float Bs[16][68];

    const int tid = threadIdx.x;
    const int bx = blockIdx.x, by = blockIdx.y;

    const int r  = tid >> 2;
    const int c4 = (tid & 3) * 4;
    const int tx = tid & 15, ty = tid >> 4;

    const float* arow;
    if constexpr (GATHER)
        arow = A + (long long)gidx[by * 64 + r] * K + c4;
    else
        arow = A + (long long)(by * 64 + r) * K + c4;

    const float* brow_bt = Bm + (long long)(bx * 64 + r) * K + c4;

    float acc[4][4] = {};

    for (int k0 = 0; k0 < K; k0 += 16) {
        float4 av = *(const float4*)(arow + k0);
        As[c4 + 0][r] = av.x; As[c4 + 1][r] = av.y;
        As[c4 + 2][r] = av.z; As[c4 + 3][r] = av.w;
        float4 bv = *(const float4*)(brow_bt + k0);
        Bs[c4 + 0][r] = bv.x; Bs[c4 + 1][r] = bv.y;
        Bs[c4 + 2][r] = bv.z; Bs[c4 + 3][r] = bv.w;
        __syncthreads();
        #pragma unroll
        for (int k2 = 0; k2 < 16; ++k2) {
            float4 a = *(const float4*)&As[k2][ty * 4];
            float4 b = *(const float4*)&Bs[k2][tx * 4];
            acc[0][0] += a.x * b.x; acc[0][1] += a.x * b.y; acc[0][2] += a.x * b.z; acc[0][3] += a.x * b.w;
            acc[1][0] += a.y * b.x; acc[1][1] += a.y * b.y; acc[1][2] += a.y * b.z; acc[1][3] += a.y * b.w;
            acc[2][0] += a.z * b.x; acc[2][1] += a.z * b.y; acc[2][2] += a.z * b.z; acc[2][3] += a.z * b.w;
            acc[3][0] += a.w * b.x; acc[3][1] += a.w * b.y; acc[3][2] += a.w * b.z; acc[3][3] += a.w * b.w;
        }
        __syncthreads();
    }

    const int row0 = by * 64 + ty * 4;
    const int col0 = bx * 64 + tx * 4;
    #pragma unroll
    for (int i = 0; i < 4; ++i) {
        float o[4];
        #pragma unroll
        for (int j = 0; j < 4; ++j) {
            int col = col0 + j;
            o[j] = acc[i][j] + bias1[col] + bias2[col];
        }
        *(float4*)(C + (long long)(row0 + i) * N + col0) =
            make_float4(o[0], o[1], o[2], o[3]);
    }
}

// ---------------------------------------------------------------------------
// Persistent RNN v3: tagged-pair publication (data+flag fused in one 64-bit
// word). hpair[2][4096]: (float h bits, uint tag=step+1), double-buffered by
// t&1. Producer: one relaxed agent 8B store per element. Consumer: batch of 8
// coherent dwordx4 loads (16 pairs) per thread = one IF round trip, data
// arrives with the successful tag check. No fences anywhere.
// ---------------------------------------------------------------------------
__global__ __launch_bounds__(256)
void rnn_kernel(const float* __restrict__ U,
                const float* __restrict__ Whh,
                float*       __restrict__ HS,
                unsigned long long* __restrict__ hpair)
{
    __shared__ float hs_s[4][1084];       // skewed: idx = k + ((k>>6)<<2)
    __shared__ float red_s[4][4][16];     // [wave][b][dl]

    const int tid = threadIdx.x;
    const int g = blockIdx.x;
    const int kq = tid >> 4, dl = tid & 15;
    const int d_own = g * 16 + dl;
    const int wv = tid >> 6;
    const int lane = tid & 63;

    float4 wreg[16];
    #pragma unroll
    for (int j4 = 0; j4 < 16; ++j4)
        wreg[j4] = *(const float4*)(Whh + (long long)d_own * DD + kq * 64 + j4 * 4);

    for (int t = 0; t < SS; ++t) {
        float u_pre = 0.f;
        if (tid < 64) {
            int b = tid >> 4, d2 = tid & 15;
            u_pre = U[((size_t)(b * SS + t)) * DD + g * 16 + d2];
        }

        if (t > 0) {
            // batch coherent poll: 16 pairs (128 B) per thread, 1 RT when hit
            const char* pb = (const char*)(hpair + (size_t)((t - 1) & 1) * 4096)
                             + tid * 128;
            uint4 q0, q1, q2, q3, q4, q5, q6, q7;
            const unsigned tg = (unsigned)t;
            for (;;) {
                asm volatile(
                    "global_load_dwordx4 %0, %8, off sc0 sc1\n\t"
                    "global_load_dwordx4 %1, %8, off offset:16 sc0 sc1\n\t"
                    "global_load_dwordx4 %2, %8, off offset:32 sc0 sc1\n\t"
                    "global_load_dwordx4 %3, %8, off offset:48 sc0 sc1\n\t"
                    "global_load_dwordx4 %4, %8, off offset:64 sc0 sc1\n\t"
                    "global_load_dwordx4 %5, %8, off offset:80 sc0 sc1\n\t"
                    "global_load_dwordx4 %6, %8, off offset:96 sc0 sc1\n\t"
                    "global_load_dwordx4 %7, %8, off offset:112 sc0 sc1\n\t"
                    "s_waitcnt vmcnt(0)"
                    : "=&v"(q0), "=&v"(q1), "=&v"(q2), "=&v"(q3),
                      "=&v"(q4), "=&v"(q5), "=&v"(q6), "=&v"(q7)
                    : "v"(pb)
                    : "memory");
                bool ok = (q0.y == tg) & (q0.w == tg) & (q1.y == tg) & (q1.w == tg)
                        & (q2.y == tg) & (q2.w == tg) & (q3.y == tg) & (q3.w == tg)
                        & (q4.y == tg) & (q4.w == tg) & (q5.y == tg) & (q5.w == tg)
                        & (q6.y == tg) & (q6.w == tg) & (q7.y == tg) & (q7.w == tg);
                if (ok) break;
                __builtin_amdgcn_s_sleep(1);
            }
            // scatter 16 h values into skewed LDS (same 64-chunk -> contiguous)
            {
                int b = tid >> 6;
                int k0 = (tid & 63) * 16;
                int ks = k0 + ((k0 >> 6) << 2);
                float* dst = &hs_s[b][ks];
                *(float4*)(dst + 0) = make_float4(
                    __uint_as_float(q0.x), __uint_as_float(q0.z),
                    __uint_as_float(q1.x), __uint_as_float(q1.z));
                *(float4*)(dst + 4) = make_float4(
                    __uint_as_float(q2.x), __uint_as_float(q2.z),
                    __uint_as_float(q3.x), __uint_as_float(q3.z));
                *(float4*)(dst + 8) = make_float4(
                    __uint_as_float(q4.x), __uint_as_float(q4.z),
                    __uint_as_float(q5.x), __uint_as_float(q5.z));
                *(float4*)(dst + 12) = make_float4(
                    __uint_as_float(q6.x), __uint_as_float(q6.z),
                    __uint_as_float(q7.x), __uint_as_float(q7.z));
            }
            __syncthreads();

            float acc0 = 0.f, acc1 = 0.f, acc2 = 0.f, acc3 = 0.f;
            const int hbase = kq * 68;
            #pragma unroll
            for (int j4 = 0; j4 < 16; ++j4) {
                float4 w4 = wreg[j4];
                float4 h0 = *(const float4*)&hs_s[0][hbase + j4 * 4];
                float4 h1 = *(const float4*)&hs_s[1][hbase + j4 * 4];
                float4 h2 = *(const float4*)&hs_s[2][hbase + j4 * 4];
                float4 h3 = *(const float4*)&hs_s[3][hbase + j4 * 4];
                acc0 += w4.x * h0.x + w4.y * h0.y + w4.z * h0.z + w4.w * h0.w;
                acc1 += w4.x * h1.x + w4.y * h1.y + w4.z * h1.z + w4.w * h1.w;
                acc2 += w4.x * h2.x + w4.y * h2.y + w4.z * h2.z + w4.w * h2.w;
                acc3 += w4.x * h3.x + w4.y * h3.y + w4.z * h3.z + w4.w * h3.w;
            }
            acc0 += __shfl_xor(acc0, 16); acc0 += __shfl_xor(acc0, 32);
            acc1 += __shfl_xor(acc1, 16); acc1 += __shfl_xor(acc1, 32);
            acc2 += __shfl_xor(acc2, 16); acc2 += __shfl_xor(acc2, 32);
            acc3 += __shfl_xor(acc3, 16); acc3 += __shfl_xor(acc3, 32);
            if ((lane >> 4) == 0) {
                red_s[wv][0][dl] = acc0; red_s[wv][1][dl] = acc1;
                red_s[wv][2][dl] = acc2; red_s[wv][3][dl] = acc3;
            }
            __syncthreads();
        }

        if (tid < 64) {
            int b = tid >> 4, d2 = tid & 15;
            float tot = 0.f;
            if (t > 0)
                tot = red_s[0][b][d2] + red_s[1][b][d2] +
                      red_s[2][b][d2] + red_s[3][b][d2];
            int d = g * 16 + d2;
            float h = tanhf(u_pre + tot);
            HS[((size_t)(b * SS + t)) * DD + d] = h;          // plain cached store
            unsigned long long pk =
                ((unsigned long long)(unsigned)(t + 1) << 32) |
                (unsigned long long)__float_as_uint(h);
            __hip_atomic_store(&hpair[(size_t)(t & 1) * 4096 + b * 1024 + d], pk,
                               __ATOMIC_RELAXED, __HIP_MEMORY_SCOPE_AGENT);
        }
        __syncthreads();   // protect hs_s / red_s reuse next step
    }
}

// mean over s: MEANX[b][d] = (1/S) sum_s HS[b,s,d].  grid = 64
__global__ __launch_bounds__(256)
void mean_kernel(const float* __restrict__ HS, float* __restrict__ MEANX)
{
    __shared__ float red[4][64];
    const int b = blockIdx.x >> 4, dc = blockIdx.x & 15;
    const int jd = threadIdx.x & 63, sq = threadIdx.x >> 6;
    float acc = 0.f;
    const float* base = HS + (long long)b * SS * DD + dc * 64 + jd;
    for (int s = sq * 256; s < sq * 256 + 256; ++s)
        acc += base[(long long)s * DD];
    red[sq][jd] = acc;
    __syncthreads();
    if (threadIdx.x < 64) {
        float m = red[0][threadIdx.x] + red[1][threadIdx.x] +
                  red[2][threadIdx.x] + red[3][threadIdx.x];
        MEANX[b * DD + dc * 64 + threadIdx.x] = m * (1.0f / (float)SS);
    }
}

// gates = softmax(MEANX @ Wg^T); top-1 weight + index per batch. 1 block.
__global__ __launch_bounds__(256)
void gate_kernel(const float* __restrict__ MEANX, const float* __restrict__ Wg,
                 float* __restrict__ WGATE, int* __restrict__ IDX)
{
    __shared__ float sc[4][4];
    const int tid = threadIdx.x;
    const int p = tid >> 4, l = tid & 15;
    const int b = p >> 2, e = p & 3;
    float acc = 0.f;
    for (int j = 0; j < 64; ++j)
        acc += MEANX[b * DD + l * 64 + j] * Wg[e * DD + l * 64 + j];
    acc += __shfl_xor(acc, 1); acc += __shfl_xor(acc, 2);
    acc += __shfl_xor(acc, 4); acc += __shfl_xor(acc, 8);
    if (l == 0) sc[b][e] = acc;
    __syncthreads();
    if (tid < 4) {
        float s0 = sc[tid][0], s1 = sc[tid][1], s2 = sc[tid][2], s3 = sc[tid][3];
        float mx = fmaxf(fmaxf(s0, s1), fmaxf(s2, s3));
        float e0 = expf(s0 - mx), e1 = expf(s1 - mx);
        float e2 = expf(s2 - mx), e3 = expf(s3 - mx);
        float inv = 1.0f / (e0 + e1 + e2 + e3);
        float pr[4] = {e0 * inv, e1 * inv, e2 * inv, e3 * inv};
        int arg = 0; float best = pr[0];
        if (pr[1] > best) { best = pr[1]; arg = 1; }
        if (pr[2] > best) { best = pr[2]; arg = 2; }
        if (pr[3] > best) { best = pr[3]; arg = 3; }
        WGATE[tid] = best;
        IDX[tid] = arg;
    }
}

// fp32 -> bf16 cast, float4-granular, grid-stride
__global__ __launch_bounds__(256)
void cast_kernel(const float* __restrict__ in, unsigned short* __restrict__ out,
                 long long n4)
{
    long long stride = (long long)gridDim.x * blockDim.x;
    for (long long i = (long long)blockIdx.x * blockDim.x + threadIdx.x;
         i < n4; i += stride) {
        float4 v = ((const float4*)in)[i];
        ushort4 o;
        o.x = f2b(v.x); o.y = f2b(v.y); o.z = f2b(v.z); o.w = f2b(v.w);
        ((ushort4*)out)[i] = o;
    }
}

// transpose-cast: src fp32 [R][C] (expert expIdx[z]) -> dst bf16 [C][R] (z)
__global__ __launch_bounds__(256)
void transpose_cast(const float* __restrict__ src, const int* __restrict__ expIdx,
                    unsigned short* __restrict__ dst, int R, int C,
                    long long srcExpStride, long long dstZStride)
{
    __shared__ float tbuf[32][33];
    const int tid = threadIdx.x;
    const int z = blockIdx.z;
    const float* S = src + (long long)expIdx[z] * srcExpStride;
    unsigned short* D = dst + (long long)z * dstZStride;
    const int r0 = blockIdx.y * 32, c0 = blockIdx.x * 32;
    const int tr = tid >> 3, tc = (tid & 7) * 4;
    float4 v = *(const float4*)(S + (long long)(r0 + tr) * C + c0 + tc);
    tbuf[tr][tc + 0] = v.x; tbuf[tr][tc + 1] = v.y;
    tbuf[tr][tc + 2] = v.z; tbuf[tr][tc + 3] = v.w;
    __syncthreads();
    ushort4 o;
    o.x = f2b(tbuf[tc + 0][tr]); o.y = f2b(tbuf[tc + 1][tr]);
    o.z = f2b(tbuf[tc + 2][tr]); o.w = f2b(tbuf[tc + 3][tr]);
    *(ushort4*)(D + (long long)(c0 + tr) * R + r0 + tc) = o;
}

// ---------------------------------------------------------------------------
// bf16 MFMA GEMM (m97 structure): C = A[M][K] @ Bt[N][K]^T, fused epilogues.
// EPI 0: +bias -> fp32 out | EPI 1: gelu(x+bias[e]) -> bf16 | EPI 2: (x+bias[e])*w -> bf16
// ---------------------------------------------------------------------------
__device__ __forceinline__ void load_lds16(const void* g, void* l) {
    __builtin_amdgcn_global_load_lds(
        (const __attribute__((address_space(1))) unsigned int*)g,
        (__attribute__((address_space(3))) unsigned int*)l, 16, 0, 0);
}

template<int EPI>
__global__ __launch_bounds__(256)
void gemm_bf16(const unsigned short* __restrict__ A,
               const unsigned short* __restrict__ Bt,
               const float* __restrict__ bias,
               void* __restrict__ Cv,
               int N, int K,
               long long aStride, long long cStride, long long btStride,
               const float* __restrict__ scaleP, const int* __restrict__ expIdx)
{
    __shared__ __align__(16) unsigned short Asm[128 * 32];
    __shared__ __align__(16) unsigned short Bsm[128 * 32];

    const int tid = threadIdx.x;
    const int wave = tid >> 6, lane = tid & 63;
    const int bm = blockIdx.y * 128, bn = blockIdx.x * 128;
    const int bz = blockIdx.z;
    const int wm = (wave >> 1) * 64, wn = (wave & 1) * 64;
    const int fr = lane & 15, kh = lane >> 4;

    const unsigned short* Az  = A  + (long long)bz * aStride;
    const unsigned short* Btz = Bt + (long long)bz * btStride;
    const float* bp = bias + (expIdx ? (long long)expIdx[bz] * N : 0);

    const int lo0 = wave * 1024 + lane * 16;
    const int lo1 = 4096 + lo0;
    const int r0 = lo0 >> 6, q0 = (lo0 & 63) >> 1;
    const int r1 = lo1 >> 6, q1 = (lo1 & 63) >> 1;
    const unsigned short* a0 = Az  + (size_t)(bm + r0) * K + q0;
    const unsigned short* a1 = Az  + (size_t)(bm + r1) * K + q1;
    const unsigned short* b0 = Btz + (size_t)(bn + r0) * K + q0;
    const unsigned short* b1 = Btz + (size_t)(bn + r1) * K + q1;

    v4f acc[4][4];
    #pragma unroll
    for (int i = 0; i < 4; ++i)
        #pragma unroll
        for (int j = 0; j < 4; ++j) {
            acc[i][j][0] = 0.f; acc[i][j][1] = 0.f;
            acc[i][j][2] = 0.f; acc[i][j][3] = 0.f;
        }

    for (int k0 = 0; k0 < K; k0 += 32) {
        load_lds16(a0 + k0, (char*)Asm + wave * 1024);
        load_lds16(a1 + k0, (char*)Asm + 4096 + wave * 1024);
        load_lds16(b0 + k0, (char*)Bsm + wave * 1024);
        load_lds16(b1 + k0, (char*)Bsm + 4096 + wave * 1024);
        __syncthreads();

        v8s af[4], bfv[4];
        #pragma unroll
        for (int f = 0; f < 4; ++f) {
            af[f]  = *(const v8s*)((const char*)Asm + ((wm + f * 16 + fr) << 6) + (kh << 4));
            bfv[f] = *(const v8s*)((const char*)Bsm + ((wn + f * 16 + fr) << 6) + (kh << 4));
        }
        #pragma unroll
        for (int fi = 0; fi < 4; ++fi)
            #pragma unroll
            for (int fj = 0; fj < 4; ++fj)
                acc[fi][fj] = __builtin_amdgcn_mfma_f32_16x16x32_bf16(
                    af[fi], bfv[fj], acc[fi][fj], 0, 0, 0);
        __syncthreads();
    }

    const float scale = (EPI == 2) ? scaleP[bz] : 1.0f;
    #pragma unroll
    for (int fi = 0; fi < 4; ++fi) {
        #pragma unroll
        for (int fj = 0; fj < 4; ++fj) {
            v4f t = acc[fi][fj];
            int col = bn + wn + fj * 16 + fr;
            float bb = bp[col];
            int rbase = bm + wm + fi * 16 + (kh << 2);
            #pragma unroll
            for (int r = 0; r < 4; ++r) {
                float v = t[r] + bb;
                if constexpr (EPI == 1)
                    v = 0.5f * v * (1.0f + erff(v * 0.70710678118654752440f));
                if constexpr (EPI == 2)
                    v *= scale;
                size_t off = (size_t)bz * (size_t)cStride +
                             (size_t)(rbase + r) * N + col;
                if constexpr (EPI == 0)
                    ((float*)Cv)[off] = v;
                else
                    ((unsigned short*)Cv)[off] = f2b(v);
            }
        }
    }
}

// ---------------------------------------------------------------------------
extern "C" void kernel_launch(void* const* d_in, const int* in_sizes, int n_in,
                              void* d_out, int out_size, void* d_ws, size_t ws_size,
                              hipStream_t stream)
{
    const int*   tokens = (const int*)  d_in[0];
    const float* emb    = (const float*)d_in[1];
    const float* Wih    = (const float*)d_in[2];
    const float* bih    = (const float*)d_in[3];
    const float* Whh    = (const float*)d_in[4];
    const float* bhh    = (const float*)d_in[5];
    const float* Wg     = (const float*)d_in[6];
    const float* W1     = (const float*)d_in[7];
    const float* b1     = (const float*)d_in[8];
    const float* W2     = (const float*)d_in[9];
    const float* b2     = (const float*)d_in[10];
    const float* Wfc    = (const float*)d_in[11];
    const float* bfc    = (const float*)d_in[12];
    float* out = (float*)d_out;
    float* ws  = (float*)d_ws;

    // ws layout (float offsets), ~117.4 MB, aliased by lifetime:
    float*          U     = ws;                                   // 4,194,304
    float*          HS    = ws + 4194304;                         // 4,194,304
    unsigned short* HSbf  = (unsigned short*)(ws + 8388608);      // 2,097,152 fl
    float*          Ebase = ws + 10485760;                        // 8,388,608 fl
    float*          Fbase = ws + 18874368;                        // 8,388,608 fl
    unsigned short* Ybf   = (unsigned short*)(ws + 27262976);     // 2,097,152 fl
    float*          MEANX = ws + 29360128;                        // 4096
    float*          WGATE = ws + 29364224;                        // 4
    int*            IDX   = (int*)(ws + 29364228);                // 4
    // aliases:
    unsigned long long* HPAIR = (unsigned long long*)Ebase;       // 64 KB, RNN only
    unsigned short* W1T   = (unsigned short*)Ebase;  // then W2T; both 32 MB
    unsigned short* W2T   = (unsigned short*)Ebase;
    unsigned short* H1bf  = (unsigned short*)Fbase;               // 32 MB
    unsigned short* Wfcbf = (unsigned short*)Ebase;               // 62.5 MB spans E+F

    hipMemsetAsync(HPAIR, 0, 2 * 4096 * sizeof(unsigned long long), stream);

    // U = emb[tokens] @ Wih^T + bih + bhh   (fp32: keeps gate path exact)
    gemm_f32<0, 0, true><<<dim3(DD / 64, (BB * SS) / 64, 1), 256, 0, stream>>>(
        emb, tokens, Wih, bih, bhh, U, DD, DD);

    // RNN scan (tagged-pair sync)
    rnn_kernel<<<64, 256, 0, stream>>>(U, Whh, HS, HPAIR);

    // gate (exact fp32 path)
    mean_kernel<<<64, 256, 0, stream>>>(HS, MEANX);
    gate_kernel<<<1, 256, 0, stream>>>(MEANX, Wg, WGATE, IDX);

    // bf16 activations for MoE
    cast_kernel<<<1024, 256, 0, stream>>>(HS, HSbf, (long long)(BB * SS) * DD / 4);

    // W1T[z] = bf16(W1[idx[z]]^T)  [DFF][DD]
    transpose_cast<<<dim3(DFF / 32, DD / 32, BB), 256, 0, stream>>>(
        W1, IDX, W1T, DD, DFF, (long long)DD * DFF, (long long)DFF * DD);

    // H1bf = gelu(HSbf @ W1T^T + b1[e])  (bf16 out)
    gemm_bf16<1><<<dim3(DFF / 128, SS / 128, BB), 256, 0, stream>>>(
        HSbf, W1T, b1, H1bf, DFF, DD,
        (long long)SS * DD, (long long)SS * DFF, (long long)DFF * DD,
        nullptr, IDX);

    // W2T[z] = bf16(W2[idx[z]]^T)  [DD][DFF]   (clobbers W1T: dead)
    transpose_cast<<<dim3(DD / 32, DFF / 32, BB), 256, 0, stream>>>(
        W2, IDX, W2T, DFF, DD, (long long)DFF * DD, (long long)DD * DFF);

    // Ybf = (H1bf @ W2T^T + b2[e]) * w  (bf16 out)
    gemm_bf16<2><<<dim3(DD / 128, SS / 128, BB), 256, 0, stream>>>(
        H1bf, W2T, b2, Ybf, DD, DFF,
        (long long)SS * DFF, (long long)SS * DD, (long long)DD * DFF,
        WGATE, IDX);

    // Wfc -> bf16 (clobbers W2T + H1bf: dead)
    cast_kernel<<<4096, 256, 0, stream>>>(Wfc, (unsigned short*)Wfcbf,
                                          (long long)VOC * DD / 4);

    // logits = Ybf @ Wfcbf^T + bfc  (fp32 out)
    gemm_bf16<0><<<dim3(VOC / 128, (BB * SS) / 128, 1), 256, 0, stream>>>(
        Ybf, Wfcbf, bfc, out, VOC, DD, 0, 0, 0, nullptr, nullptr);
}

// Round 4
// 2945.760 us; speedup vs baseline: 5.0914x; 1.5419x over previous
//
#include <hip/hip_runtime.h>
#include <hip/hip_bf16.h>
#include <math.h>

#define DD    1024
#define SS    1024
#define BB    4
#define EE    4
#define DFF   4096
#define VOC   32000

typedef __attribute__((ext_vector_type(8))) short v8s;   // 8 bf16 (4 VGPRs)
typedef __attribute__((ext_vector_type(4))) float v4f;   // MFMA accumulator

// fp32 -> bf16 (RNE)
__device__ __forceinline__ unsigned short f2b(float f) {
    unsigned u = __float_as_uint(f);
    unsigned r = (u + 0x7FFFu + ((u >> 16) & 1u)) >> 16;
    return (unsigned short)r;
}

// ---------------------------------------------------------------------------
// fp32 tiled GEMM (only used for U = emb[tok] @ Wih^T + bih + bhh).
// ---------------------------------------------------------------------------
template<int BMODE, int EPI, bool GATHER>
__global__ __launch_bounds__(256)
void gemm_f32(const float* __restrict__ A,
              const int*   __restrict__ gidx,
              const float* __restrict__ Bm,
              const float* __restrict__ bias1,
              const float* __restrict__ bias2,
              float*       __restrict__ C,
              int K, int N)
{
    __shared__ float As[16][68];
    __shared__ float Bs[16][68];

    const int tid = threadIdx.x;
    const int bx = blockIdx.x, by = blockIdx.y;

    const int r  = tid >> 2;
    const int c4 = (tid & 3) * 4;
    const int tx = tid & 15, ty = tid >> 4;

    const float* arow;
    if constexpr (GATHER)
        arow = A + (long long)gidx[by * 64 + r] * K + c4;
    else
        arow = A + (long long)(by * 64 + r) * K + c4;

    const float* brow_bt = Bm + (long long)(bx * 64 + r) * K + c4;

    float acc[4][4] = {};

    for (int k0 = 0; k0 < K; k0 += 16) {
        float4 av = *(const float4*)(arow + k0);
        As[c4 + 0][r] = av.x; As[c4 + 1][r] = av.y;
        As[c4 + 2][r] = av.z; As[c4 + 3][r] = av.w;
        float4 bv = *(const float4*)(brow_bt + k0);
        Bs[c4 + 0][r] = bv.x; Bs[c4 + 1][r] = bv.y;
        Bs[c4 + 2][r] = bv.z; Bs[c4 + 3][r] = bv.w;
        __syncthreads();
        #pragma unroll
        for (int k2 = 0; k2 < 16; ++k2) {
            float4 a = *(const float4*)&As[k2][ty * 4];
            float4 b = *(const float4*)&Bs[k2][tx * 4];
            acc[0][0] += a.x * b.x; acc[0][1] += a.x * b.y; acc[0][2] += a.x * b.z; acc[0][3] += a.x * b.w;
            acc[1][0] += a.y * b.x; acc[1][1] += a.y * b.y; acc[1][2] += a.y * b.z; acc[1][3] += a.y * b.w;
            acc[2][0] += a.z * b.x; acc[2][1] += a.z * b.y; acc[2][2] += a.z * b.z; acc[2][3] += a.z * b.w;
            acc[3][0] += a.w * b.x; acc[3][1] += a.w * b.y; acc[3][2] += a.w * b.z; acc[3][3] += a.w * b.w;
        }
        __syncthreads();
    }

    const int row0 = by * 64 + ty * 4;
    const int col0 = bx * 64 + tx * 4;
    #pragma unroll
    for (int i = 0; i < 4; ++i) {
        float o[4];
        #pragma unroll
        for (int j = 0; j < 4; ++j) {
            int col = col0 + j;
            o[j] = acc[i][j] + bias1[col] + bias2[col];
        }
        *(float4*)(C + (long long)(row0 + i) * N + col0) =
            make_float4(o[0], o[1], o[2], o[3]);
    }
}

// ---------------------------------------------------------------------------
// Persistent RNN v4: 64 blocks x 1024 threads (4 waves/SIMD for latency
// hiding). Tagged-pair publication kept (1 IF round trip). 16 threads per
// output: thread (out=tid>>4, chunk=tid&15) holds Whh[d_own][chunk*64..+64)
// in 16 float4 regs. Poll: 32 B/thread (2 dwordx4 sc0 sc1). Redistribute via
// one ds_write_b128 + barrier; matvec = 16 ds_read_b128 (4-lane broadcast,
// ~2-way banks) + 64 FMA; 4-level shfl_xor reduce; per-wave early publish.
// Double-buffer parity safety: a block reaching step t+1 implies every block
// passed its step-t poll, so overwriting buffer (t+1)&1 is safe.
// ---------------------------------------------------------------------------
__global__ __launch_bounds__(1024)
void rnn_kernel(const float* __restrict__ U,
                const float* __restrict__ Whh,
                float*       __restrict__ HS,
                unsigned long long* __restrict__ hpair)
{
    __shared__ float hs_s[4 * 1088];      // per-batch rows, +4-per-64 skew

    const int tid = threadIdx.x;
    const int g = blockIdx.x;
    const int out = tid >> 4;             // 0..63
    const int chunk = tid & 15;           // 0..15
    const int b = out >> 4;               // 0..3
    const int dl = out & 15;              // 0..15
    const int d_own = g * 16 + dl;
    const bool is_res = (chunk == 0);     // lanes 0,16,32,48 of each wave

    float4 wreg[16];
    #pragma unroll
    for (int j = 0; j < 16; ++j)
        wreg[j] = *(const float4*)(Whh + (size_t)d_own * DD + chunk * 64 + j * 4);

    // scatter destination (this thread's 4 polled h values)
    const int sb = tid >> 8;              // batch of scattered elems
    const int sk = (tid & 255) * 4;       // float offset within batch row
    float* sdst = &hs_s[sb * 1088 + sk + ((sk >> 6) << 2)];
    // read base for the matvec slice
    const float* rbase = &hs_s[b * 1088 + chunk * 68];

    for (int t = 0; t < SS; ++t) {
        // independent prefetch of this step's U value
        float u_pre = 0.f;
        if (is_res)
            u_pre = U[((size_t)(b * SS + t)) * DD + d_own];

        if (t > 0) {
            const char* pb = (const char*)(hpair + (size_t)((t - 1) & 1) * 4096)
                             + tid * 32;
            uint4 q0, q1;
            const unsigned tg = (unsigned)t;
            for (;;) {
                asm volatile(
                    "global_load_dwordx4 %0, %2, off sc0 sc1\n\t"
                    "global_load_dwordx4 %1, %2, off offset:16 sc0 sc1\n\t"
                    "s_waitcnt vmcnt(0)"
                    : "=&v"(q0), "=&v"(q1)
                    : "v"(pb)
                    : "memory");
                if ((q0.y == tg) & (q0.w == tg) & (q1.y == tg) & (q1.w == tg))
                    break;
                __builtin_amdgcn_s_sleep(1);
            }
            *(float4*)sdst = make_float4(
                __uint_as_float(q0.x), __uint_as_float(q0.z),
                __uint_as_float(q1.x), __uint_as_float(q1.z));
        }
        __syncthreads();

        float acc = 0.f;
        if (t > 0) {
            #pragma unroll
            for (int j = 0; j < 16; ++j) {
                float4 h4 = *(const float4*)(rbase + j * 4);
                float4 w4 = wreg[j];
                acc += w4.x * h4.x + w4.y * h4.y + w4.z * h4.z + w4.w * h4.w;
            }
            acc += __shfl_xor(acc, 1);
            acc += __shfl_xor(acc, 2);
            acc += __shfl_xor(acc, 4);
            acc += __shfl_xor(acc, 8);
        }

        if (is_res) {
            float h = tanhf(u_pre + acc);
            HS[((size_t)(b * SS + t)) * DD + d_own] = h;     // plain cached store
            unsigned long long pk =
                ((unsigned long long)(unsigned)(t + 1) << 32) |
                (unsigned long long)__float_as_uint(h);
            __hip_atomic_store(&hpair[(size_t)(t & 1) * 4096 + b * 1024 + d_own],
                               pk, __ATOMIC_RELAXED, __HIP_MEMORY_SCOPE_AGENT);
        }
        __syncthreads();   // all reads of hs_s done before next scatter
    }
}

// mean over s: MEANX[b][d] = (1/S) sum_s HS[b,s,d].  grid = 64
__global__ __launch_bounds__(256)
void mean_kernel(const float* __restrict__ HS, float* __restrict__ MEANX)
{
    __shared__ float red[4][64];
    const int b = blockIdx.x >> 4, dc = blockIdx.x & 15;
    const int jd = threadIdx.x & 63, sq = threadIdx.x >> 6;
    float acc = 0.f;
    const float* base = HS + (long long)b * SS * DD + dc * 64 + jd;
    for (int s = sq * 256; s < sq * 256 + 256; ++s)
        acc += base[(long long)s * DD];
    red[sq][jd] = acc;
    __syncthreads();
    if (threadIdx.x < 64) {
        float m = red[0][threadIdx.x] + red[1][threadIdx.x] +
                  red[2][threadIdx.x] + red[3][threadIdx.x];
        MEANX[b * DD + dc * 64 + threadIdx.x] = m * (1.0f / (float)SS);
    }
}

// gates = softmax(MEANX @ Wg^T); top-1 weight + index per batch. 1 block.
__global__ __launch_bounds__(256)
void gate_kernel(const float* __restrict__ MEANX, const float* __restrict__ Wg,
                 float* __restrict__ WGATE, int* __restrict__ IDX)
{
    __shared__ float sc[4][4];
    const int tid = threadIdx.x;
    const int p = tid >> 4, l = tid & 15;
    const int b = p >> 2, e = p & 3;
    float acc = 0.f;
    for (int j = 0; j < 64; ++j)
        acc += MEANX[b * DD + l * 64 + j] * Wg[e * DD + l * 64 + j];
    acc += __shfl_xor(acc, 1); acc += __shfl_xor(acc, 2);
    acc += __shfl_xor(acc, 4); acc += __shfl_xor(acc, 8);
    if (l == 0) sc[b][e] = acc;
    __syncthreads();
    if (tid < 4) {
        float s0 = sc[tid][0], s1 = sc[tid][1], s2 = sc[tid][2], s3 = sc[tid][3];
        float mx = fmaxf(fmaxf(s0, s1), fmaxf(s2, s3));
        float e0 = expf(s0 - mx), e1 = expf(s1 - mx);
        float e2 = expf(s2 - mx), e3 = expf(s3 - mx);
        float inv = 1.0f / (e0 + e1 + e2 + e3);
        float pr[4] = {e0 * inv, e1 * inv, e2 * inv, e3 * inv};
        int arg = 0; float best = pr[0];
        if (pr[1] > best) { best = pr[1]; arg = 1; }
        if (pr[2] > best) { best = pr[2]; arg = 2; }
        if (pr[3] > best) { best = pr[3]; arg = 3; }
        WGATE[tid] = best;
        IDX[tid] = arg;
    }
}

// fp32 -> bf16 cast, float4-granular, grid-stride
__global__ __launch_bounds__(256)
void cast_kernel(const float* __restrict__ in, unsigned short* __restrict__ out,
                 long long n4)
{
    long long stride = (long long)gridDim.x * blockDim.x;
    for (long long i = (long long)blockIdx.x * blockDim.x + threadIdx.x;
         i < n4; i += stride) {
        float4 v = ((const float4*)in)[i];
        ushort4 o;
        o.x = f2b(v.x); o.y = f2b(v.y); o.z = f2b(v.z); o.w = f2b(v.w);
        ((ushort4*)out)[i] = o;
    }
}

// transpose-cast: src fp32 [R][C] (expert expIdx[z]) -> dst bf16 [C][R] (z)
__global__ __launch_bounds__(256)
void transpose_cast(const float* __restrict__ src, const int* __restrict__ expIdx,
                    unsigned short* __restrict__ dst, int R, int C,
                    long long srcExpStride, long long dstZStride)
{
    __shared__ float tbuf[32][33];
    const int tid = threadIdx.x;
    const int z = blockIdx.z;
    const float* S = src + (long long)expIdx[z] * srcExpStride;
    unsigned short* D = dst + (long long)z * dstZStride;
    const int r0 = blockIdx.y * 32, c0 = blockIdx.x * 32;
    const int tr = tid >> 3, tc = (tid & 7) * 4;
    float4 v = *(const float4*)(S + (long long)(r0 + tr) * C + c0 + tc);
    tbuf[tr][tc + 0] = v.x; tbuf[tr][tc + 1] = v.y;
    tbuf[tr][tc + 2] = v.z; tbuf[tr][tc + 3] = v.w;
    __syncthreads();
    ushort4 o;
    o.x = f2b(tbuf[tc + 0][tr]); o.y = f2b(tbuf[tc + 1][tr]);
    o.z = f2b(tbuf[tc + 2][tr]); o.w = f2b(tbuf[tc + 3][tr]);
    *(ushort4*)(D + (long long)(c0 + tr) * R + r0 + tc) = o;
}

// ---------------------------------------------------------------------------
// bf16 MFMA GEMM (m97 structure): C = A[M][K] @ Bt[N][K]^T, fused epilogues.
// EPI 0: +bias -> fp32 out | EPI 1: gelu(x+bias[e]) -> bf16 | EPI 2: (x+bias[e])*w -> bf16
// ---------------------------------------------------------------------------
__device__ __forceinline__ void load_lds16(const void* g, void* l) {
    __builtin_amdgcn_global_load_lds(
        (const __attribute__((address_space(1))) unsigned int*)g,
        (__attribute__((address_space(3))) unsigned int*)l, 16, 0, 0);
}

template<int EPI>
__global__ __launch_bounds__(256)
void gemm_bf16(const unsigned short* __restrict__ A,
               const unsigned short* __restrict__ Bt,
               const float* __restrict__ bias,
               void* __restrict__ Cv,
               int N, int K,
               long long aStride, long long cStride, long long btStride,
               const float* __restrict__ scaleP, const int* __restrict__ expIdx)
{
    __shared__ __align__(16) unsigned short Asm[128 * 32];
    __shared__ __align__(16) unsigned short Bsm[128 * 32];

    const int tid = threadIdx.x;
    const int wave = tid >> 6, lane = tid & 63;
    const int bm = blockIdx.y * 128, bn = blockIdx.x * 128;
    const int bz = blockIdx.z;
    const int wm = (wave >> 1) * 64, wn = (wave & 1) * 64;
    const int fr = lane & 15, kh = lane >> 4;

    const unsigned short* Az  = A  + (long long)bz * aStride;
    const unsigned short* Btz = Bt + (long long)bz * btStride;
    const float* bp = bias + (expIdx ? (long long)expIdx[bz] * N : 0);

    const int lo0 = wave * 1024 + lane * 16;
    const int lo1 = 4096 + lo0;
    const int r0 = lo0 >> 6, q0 = (lo0 & 63) >> 1;
    const int r1 = lo1 >> 6, q1 = (lo1 & 63) >> 1;
    const unsigned short* a0 = Az  + (size_t)(bm + r0) * K + q0;
    const unsigned short* a1 = Az  + (size_t)(bm + r1) * K + q1;
    const unsigned short* b0 = Btz + (size_t)(bn + r0) * K + q0;
    const unsigned short* b1 = Btz + (size_t)(bn + r1) * K + q1;

    v4f acc[4][4];
    #pragma unroll
    for (int i = 0; i < 4; ++i)
        #pragma unroll
        for (int j = 0; j < 4; ++j) {
            acc[i][j][0] = 0.f; acc[i][j][1] = 0.f;
            acc[i][j][2] = 0.f; acc[i][j][3] = 0.f;
        }

    for (int k0 = 0; k0 < K; k0 += 32) {
        load_lds16(a0 + k0, (char*)Asm + wave * 1024);
        load_lds16(a1 + k0, (char*)Asm + 4096 + wave * 1024);
        load_lds16(b0 + k0, (char*)Bsm + wave * 1024);
        load_lds16(b1 + k0, (char*)Bsm + 4096 + wave * 1024);
        __syncthreads();

        v8s af[4], bfv[4];
        #pragma unroll
        for (int f = 0; f < 4; ++f) {
            af[f]  = *(const v8s*)((const char*)Asm + ((wm + f * 16 + fr) << 6) + (kh << 4));
            bfv[f] = *(const v8s*)((const char*)Bsm + ((wn + f * 16 + fr) << 6) + (kh << 4));
        }
        #pragma unroll
        for (int fi = 0; fi < 4; ++fi)
            #pragma unroll
            for (int fj = 0; fj < 4; ++fj)
                acc[fi][fj] = __builtin_amdgcn_mfma_f32_16x16x32_bf16(
                    af[fi], bfv[fj], acc[fi][fj], 0, 0, 0);
        __syncthreads();
    }

    const float scale = (EPI == 2) ? scaleP[bz] : 1.0f;
    #pragma unroll
    for (int fi = 0; fi < 4; ++fi) {
        #pragma unroll
        for (int fj = 0; fj < 4; ++fj) {
            v4f t = acc[fi][fj];
            int col = bn + wn + fj * 16 + fr;
            float bb = bp[col];
            int rbase = bm + wm + fi * 16 + (kh << 2);
            #pragma unroll
            for (int r = 0; r < 4; ++r) {
                float v = t[r] + bb;
                if constexpr (EPI == 1)
                    v = 0.5f * v * (1.0f + erff(v * 0.70710678118654752440f));
                if constexpr (EPI == 2)
                    v *= scale;
                size_t off = (size_t)bz * (size_t)cStride +
                             (size_t)(rbase + r) * N + col;
                if constexpr (EPI == 0)
                    ((float*)Cv)[off] = v;
                else
                    ((unsigned short*)Cv)[off] = f2b(v);
            }
        }
    }
}

// ---------------------------------------------------------------------------
extern "C" void kernel_launch(void* const* d_in, const int* in_sizes, int n_in,
                              void* d_out, int out_size, void* d_ws, size_t ws_size,
                              hipStream_t stream)
{
    const int*   tokens = (const int*)  d_in[0];
    const float* emb    = (const float*)d_in[1];
    const float* Wih    = (const float*)d_in[2];
    const float* bih    = (const float*)d_in[3];
    const float* Whh    = (const float*)d_in[4];
    const float* bhh    = (const float*)d_in[5];
    const float* Wg     = (const float*)d_in[6];
    const float* W1     = (const float*)d_in[7];
    const float* b1     = (const float*)d_in[8];
    const float* W2     = (const float*)d_in[9];
    const float* b2     = (const float*)d_in[10];
    const float* Wfc    = (const float*)d_in[11];
    const float* bfc    = (const float*)d_in[12];
    float* out = (float*)d_out;
    float* ws  = (float*)d_ws;

    // ws layout (float offsets), ~117.4 MB, aliased by lifetime:
    float*          U     = ws;                                   // 4,194,304
    float*          HS    = ws + 4194304;                         // 4,194,304
    unsigned short* HSbf  = (unsigned short*)(ws + 8388608);      // 2,097,152 fl
    float*          Ebase = ws + 10485760;                        // 8,388,608 fl
    float*          Fbase = ws + 18874368;                        // 8,388,608 fl
    unsigned short* Ybf   = (unsigned short*)(ws + 27262976);     // 2,097,152 fl
    float*          MEANX = ws + 29360128;                        // 4096
    float*          WGATE = ws + 29364224;                        // 4
    int*            IDX   = (int*)(ws + 29364228);                // 4
    // aliases:
    unsigned long long* HPAIR = (unsigned long long*)Ebase;       // 64 KB, RNN only
    unsigned short* W1T   = (unsigned short*)Ebase;  // then W2T; both 32 MB
    unsigned short* W2T   = (unsigned short*)Ebase;
    unsigned short* H1bf  = (unsigned short*)Fbase;               // 32 MB
    unsigned short* Wfcbf = (unsigned short*)Ebase;               // 62.5 MB spans E+F

    hipMemsetAsync(HPAIR, 0, 2 * 4096 * sizeof(unsigned long long), stream);

    // U = emb[tokens] @ Wih^T + bih + bhh   (fp32: keeps gate path exact)
    gemm_f32<0, 0, true><<<dim3(DD / 64, (BB * SS) / 64, 1), 256, 0, stream>>>(
        emb, tokens, Wih, bih, bhh, U, DD, DD);

    // RNN scan (tagged-pair sync, 1024-thread blocks)
    rnn_kernel<<<64, 1024, 0, stream>>>(U, Whh, HS, HPAIR);

    // gate (exact fp32 path)
    mean_kernel<<<64, 256, 0, stream>>>(HS, MEANX);
    gate_kernel<<<1, 256, 0, stream>>>(MEANX, Wg, WGATE, IDX);

    // bf16 activations for MoE
    cast_kernel<<<1024, 256, 0, stream>>>(HS, HSbf, (long long)(BB * SS) * DD / 4);

    // W1T[z] = bf16(W1[idx[z]]^T)  [DFF][DD]
    transpose_cast<<<dim3(DFF / 32, DD / 32, BB), 256, 0, stream>>>(
        W1, IDX, W1T, DD, DFF, (long long)DD * DFF, (long long)DFF * DD);

    // H1bf = gelu(HSbf @ W1T^T + b1[e])  (bf16 out)
    gemm_bf16<1><<<dim3(DFF / 128, SS / 128, BB), 256, 0, stream>>>(
        HSbf, W1T, b1, H1bf, DFF, DD,
        (long long)SS * DD, (long long)SS * DFF, (long long)DFF * DD,
        nullptr, IDX);

    // W2T[z] = bf16(W2[idx[z]]^T)  [DD][DFF]   (clobbers W1T: dead)
    transpose_cast<<<dim3(DD / 32, DFF / 32, BB), 256, 0, stream>>>(
        W2, IDX, W2T, DFF, DD, (long long)DFF * DD, (long long)DD * DFF);

    // Ybf = (H1bf @ W2T^T + b2[e]) * w  (bf16 out)
    gemm_bf16<2><<<dim3(DD / 128, SS / 128, BB), 256, 0, stream>>>(
        H1bf, W2T, b2, Ybf, DD, DFF,
        (long long)SS * DFF, (long long)SS * DD, (long long)DD * DFF,
        WGATE, IDX);

    // Wfc -> bf16 (clobbers W2T + H1bf: dead)
    cast_kernel<<<4096, 256, 0, stream>>>(Wfc, (unsigned short*)Wfcbf,
                                          (long long)VOC * DD / 4);

    // logits = Ybf @ Wfcbf^T + bfc  (fp32 out)
    gemm_bf16<0><<<dim3(VOC / 128, (BB * SS) / 128, 1), 256, 0, stream>>>(
        Ybf, Wfcbf, bfc, out, VOC, DD, 0, 0, 0, nullptr, nullptr);
}

// Round 5
// 2824.158 us; speedup vs baseline: 5.3106x; 1.0431x over previous
//
#include <hip/hip_runtime.h>
#include <hip/hip_bf16.h>
#include <math.h>

#define DD    1024
#define SS    1024
#define BB    4
#define EE    4
#define DFF   4096
#define VOC   32000

typedef __attribute__((ext_vector_type(8))) short v8s;   // 8 bf16 (4 VGPRs)
typedef __attribute__((ext_vector_type(4))) float v4f;   // MFMA accumulator

// fp32 -> bf16 (RNE)
__device__ __forceinline__ unsigned short f2b(float f) {
    unsigned u = __float_as_uint(f);
    unsigned r = (u + 0x7FFFu + ((u >> 16) & 1u)) >> 16;
    return (unsigned short)r;
}
__device__ __forceinline__ float b2f(unsigned short h) {
    return __uint_as_float((unsigned)h << 16);
}

// bijective XCD-aware block swizzle (m204): safe for any nwg
__device__ __forceinline__ void xcd_swizzle(int& bx, int& by) {
    int gx = gridDim.x;
    int nwg = gx * gridDim.y;
    int id = by * gx + bx;
    int q = nwg >> 3, r = nwg & 7;
    int xcd = id & 7, o = id >> 3;
    int swz = (xcd < r ? xcd * (q + 1) : r * (q + 1) + (xcd - r) * q) + o;
    bx = swz % gx; by = swz / gx;
}

// ---------------------------------------------------------------------------
// split-bf16 casts for the U GEMM (Ootomo 3-term): x = hi + lo, both bf16.
// GATHER: row -> emb[tokens[row]]
// ---------------------------------------------------------------------------
template<bool GATHER>
__global__ __launch_bounds__(256)
void split_cast(const float* __restrict__ src, const int* __restrict__ tokens,
                unsigned short* __restrict__ Xhi, unsigned short* __restrict__ Xlo)
{
    const int row = blockIdx.x;
    const float4* s;
    if constexpr (GATHER)
        s = (const float4*)(src + (size_t)tokens[row] * DD);
    else
        s = (const float4*)(src + (size_t)row * DD);
    const int c = threadIdx.x;          // 256 float4 per 1024-wide row
    float4 v = s[c];
    ushort4 hi, lo;
    hi.x = f2b(v.x); hi.y = f2b(v.y); hi.z = f2b(v.z); hi.w = f2b(v.w);
    lo.x = f2b(v.x - b2f(hi.x)); lo.y = f2b(v.y - b2f(hi.y));
    lo.z = f2b(v.z - b2f(hi.z)); lo.w = f2b(v.w - b2f(hi.w));
    ((ushort4*)Xhi)[(size_t)row * 256 + c] = hi;
    ((ushort4*)Xlo)[(size_t)row * 256 + c] = lo;
}

// ---------------------------------------------------------------------------
// Persistent RNN v5: tagged-pair sync (1 IF round trip), 64 blocks x 1024
// threads, double-buffered LDS by step parity -> ONE barrier per step.
// Safety: reads of buf[p] at step t are separated from writes of buf[p] at
// step t+2 by the step-t+1 barrier. Mean-over-t fused into publish lanes.
// ---------------------------------------------------------------------------
__global__ __launch_bounds__(1024)
void rnn_kernel(const float* __restrict__ U,
                const float* __restrict__ Whh,
                float*       __restrict__ HS,
                unsigned long long* __restrict__ hpair,
                float*       __restrict__ MEANX)
{
    __shared__ float hs_s[2][4 * 1088];   // [parity][batch row, +4/64 skew]

    const int tid = threadIdx.x;
    const int g = blockIdx.x;
    const int out = tid >> 4;             // 0..63
    const int chunk = tid & 15;           // 0..15
    const int b = out >> 4;               // 0..3
    const int dl = out & 15;              // 0..15
    const int d_own = g * 16 + dl;
    const bool is_res = (chunk == 0);

    float4 wreg[16];
    #pragma unroll
    for (int j = 0; j < 16; ++j)
        wreg[j] = *(const float4*)(Whh + (size_t)d_own * DD + chunk * 64 + j * 4);

    const int sb = tid >> 8;              // scatter batch
    const int sk = (tid & 255) * 4;       // scatter float offset
    const int sks = sk + ((sk >> 6) << 2);
    const int rofs = b * 1088 + chunk * 68;

    float m_acc = 0.f;

    for (int t = 0; t < SS; ++t) {
        float u_pre = 0.f;
        if (is_res)
            u_pre = U[((size_t)(b * SS + t)) * DD + d_own];

        const int par = t & 1;
        if (t > 0) {
            const char* pb = (const char*)(hpair + (size_t)((t - 1) & 1) * 4096)
                             + tid * 32;
            uint4 q0, q1;
            const unsigned tg = (unsigned)t;
            for (;;) {
                asm volatile(
                    "global_load_dwordx4 %0, %2, off sc0 sc1\n\t"
                    "global_load_dwordx4 %1, %2, off offset:16 sc0 sc1\n\t"
                    "s_waitcnt vmcnt(0)"
                    : "=&v"(q0), "=&v"(q1)
                    : "v"(pb)
                    : "memory");
                if ((q0.y == tg) & (q0.w == tg) & (q1.y == tg) & (q1.w == tg))
                    break;
                __builtin_amdgcn_s_sleep(1);
            }
            *(float4*)&hs_s[par][sb * 1088 + sks] = make_float4(
                __uint_as_float(q0.x), __uint_as_float(q0.z),
                __uint_as_float(q1.x), __uint_as_float(q1.z));
        }
        __syncthreads();

        float acc = 0.f;
        if (t > 0) {
            const float* rbase = &hs_s[par][rofs];
            #pragma unroll
            for (int j = 0; j < 16; ++j) {
                float4 h4 = *(const float4*)(rbase + j * 4);
                float4 w4 = wreg[j];
                acc += w4.x * h4.x + w4.y * h4.y + w4.z * h4.z + w4.w * h4.w;
            }
            acc += __shfl_xor(acc, 1);
            acc += __shfl_xor(acc, 2);
            acc += __shfl_xor(acc, 4);
            acc += __shfl_xor(acc, 8);
        }

        if (is_res) {
            float h = tanhf(u_pre + acc);
            HS[((size_t)(b * SS + t)) * DD + d_own] = h;
            m_acc += h;
            unsigned long long pk =
                ((unsigned long long)(unsigned)(t + 1) << 32) |
                (unsigned long long)__float_as_uint(h);
            __hip_atomic_store(&hpair[(size_t)(t & 1) * 4096 + b * 1024 + d_own],
                               pk, __ATOMIC_RELAXED, __HIP_MEMORY_SCOPE_AGENT);
        }
    }

    if (is_res)
        MEANX[b * DD + d_own] = m_acc * (1.0f / (float)SS);
}

// gates = softmax(MEANX @ Wg^T); top-1 weight + index per batch. 1 block.
__global__ __launch_bounds__(256)
void gate_kernel(const float* __restrict__ MEANX, const float* __restrict__ Wg,
                 float* __restrict__ WGATE, int* __restrict__ IDX)
{
    __shared__ float sc[4][4];
    const int tid = threadIdx.x;
    const int p = tid >> 4, l = tid & 15;
    const int b = p >> 2, e = p & 3;
    float acc = 0.f;
    for (int j = 0; j < 64; ++j)
        acc += MEANX[b * DD + l * 64 + j] * Wg[e * DD + l * 64 + j];
    acc += __shfl_xor(acc, 1); acc += __shfl_xor(acc, 2);
    acc += __shfl_xor(acc, 4); acc += __shfl_xor(acc, 8);
    if (l == 0) sc[b][e] = acc;
    __syncthreads();
    if (tid < 4) {
        float s0 = sc[tid][0], s1 = sc[tid][1], s2 = sc[tid][2], s3 = sc[tid][3];
        float mx = fmaxf(fmaxf(s0, s1), fmaxf(s2, s3));
        float e0 = expf(s0 - mx), e1 = expf(s1 - mx);
        float e2 = expf(s2 - mx), e3 = expf(s3 - mx);
        float inv = 1.0f / (e0 + e1 + e2 + e3);
        float pr[4] = {e0 * inv, e1 * inv, e2 * inv, e3 * inv};
        int arg = 0; float best = pr[0];
        if (pr[1] > best) { best = pr[1]; arg = 1; }
        if (pr[2] > best) { best = pr[2]; arg = 2; }
        if (pr[3] > best) { best = pr[3]; arg = 3; }
        WGATE[tid] = best;
        IDX[tid] = arg;
    }
}

// fp32 -> bf16 cast, float4-granular, grid-stride
__global__ __launch_bounds__(256)
void cast_kernel(const float* __restrict__ in, unsigned short* __restrict__ out,
                 long long n4)
{
    long long stride = (long long)gridDim.x * blockDim.x;
    for (long long i = (long long)blockIdx.x * blockDim.x + threadIdx.x;
         i < n4; i += stride) {
        float4 v = ((const float4*)in)[i];
        ushort4 o;
        o.x = f2b(v.x); o.y = f2b(v.y); o.z = f2b(v.z); o.w = f2b(v.w);
        ((ushort4*)out)[i] = o;
    }
}

// transpose-cast: src fp32 [R][C] (expert expIdx[z]) -> dst bf16 [C][R] (z)
__global__ __launch_bounds__(256)
void transpose_cast(const float* __restrict__ src, const int* __restrict__ expIdx,
                    unsigned short* __restrict__ dst, int R, int C,
                    long long srcExpStride, long long dstZStride)
{
    __shared__ float tbuf[32][33];
    const int tid = threadIdx.x;
    const int z = blockIdx.z;
    const float* S = src + (long long)expIdx[z] * srcExpStride;
    unsigned short* D = dst + (long long)z * dstZStride;
    const int r0 = blockIdx.y * 32, c0 = blockIdx.x * 32;
    const int tr = tid >> 3, tc = (tid & 7) * 4;
    float4 v = *(const float4*)(S + (long long)(r0 + tr) * C + c0 + tc);
    tbuf[tr][tc + 0] = v.x; tbuf[tr][tc + 1] = v.y;
    tbuf[tr][tc + 2] = v.z; tbuf[tr][tc + 3] = v.w;
    __syncthreads();
    ushort4 o;
    o.x = f2b(tbuf[tc + 0][tr]); o.y = f2b(tbuf[tc + 1][tr]);
    o.z = f2b(tbuf[tc + 2][tr]); o.w = f2b(tbuf[tc + 3][tr]);
    *(ushort4*)(D + (long long)(c0 + tr) * R + r0 + tc) = o;
}

// ---------------------------------------------------------------------------
// bf16 MFMA GEMM (m97 structure): C = A[M][K] @ Bt[N][K]^T, fused epilogues.
// EPI 0: +bias -> fp32 | EPI 1: gelu(x+bias[e]) -> bf16 | EPI 2: (x+bias[e])*w -> bf16
// ---------------------------------------------------------------------------
__device__ __forceinline__ void load_lds16(const void* g, void* l) {
    __builtin_amdgcn_global_load_lds(
        (const __attribute__((address_space(1))) unsigned int*)g,
        (__attribute__((address_space(3))) unsigned int*)l, 16, 0, 0);
}

template<int EPI>
__global__ __launch_bounds__(256)
void gemm_bf16(const unsigned short* __restrict__ A,
               const unsigned short* __restrict__ Bt,
               const float* __restrict__ bias,
               void* __restrict__ Cv,
               int N, int K,
               long long aStride, long long cStride, long long btStride,
               const float* __restrict__ scaleP, const int* __restrict__ expIdx)
{
    __shared__ __align__(16) unsigned short Asm[128 * 32];
    __shared__ __align__(16) unsigned short Bsm[128 * 32];

    const int tid = threadIdx.x;
    const int wave = tid >> 6, lane = tid & 63;
    int bxs = blockIdx.x, bys = blockIdx.y;
    xcd_swizzle(bxs, bys);
    const int bm = bys * 128, bn = bxs * 128;
    const int bz = blockIdx.z;
    const int wm = (wave >> 1) * 64, wn = (wave & 1) * 64;
    const int fr = lane & 15, kh = lane >> 4;

    const unsigned short* Az  = A  + (long long)bz * aStride;
    const unsigned short* Btz = Bt + (long long)bz * btStride;
    const float* bp = bias + (expIdx ? (long long)expIdx[bz] * N : 0);

    const int lo0 = wave * 1024 + lane * 16;
    const int lo1 = 4096 + lo0;
    const int r0 = lo0 >> 6, q0 = (lo0 & 63) >> 1;
    const int r1 = lo1 >> 6, q1 = (lo1 & 63) >> 1;
    const unsigned short* a0 = Az  + (size_t)(bm + r0) * K + q0;
    const unsigned short* a1 = Az  + (size_t)(bm + r1) * K + q1;
    const unsigned short* b0 = Btz + (size_t)(bn + r0) * K + q0;
    const unsigned short* b1 = Btz + (size_t)(bn + r1) * K + q1;

    v4f acc[4][4];
    #pragma unroll
    for (int i = 0; i < 4; ++i)
        #pragma unroll
        for (int j = 0; j < 4; ++j) {
            acc[i][j][0] = 0.f; acc[i][j][1] = 0.f;
            acc[i][j][2] = 0.f; acc[i][j][3] = 0.f;
        }

    for (int k0 = 0; k0 < K; k0 += 32) {
        load_lds16(a0 + k0, (char*)Asm + wave * 1024);
        load_lds16(a1 + k0, (char*)Asm + 4096 + wave * 1024);
        load_lds16(b0 + k0, (char*)Bsm + wave * 1024);
        load_lds16(b1 + k0, (char*)Bsm + 4096 + wave * 1024);
        __syncthreads();

        v8s af[4], bfv[4];
        #pragma unroll
        for (int f = 0; f < 4; ++f) {
            af[f]  = *(const v8s*)((const char*)Asm + ((wm + f * 16 + fr) << 6) + (kh << 4));
            bfv[f] = *(const v8s*)((const char*)Bsm + ((wn + f * 16 + fr) << 6) + (kh << 4));
        }
        #pragma unroll
        for (int fi = 0; fi < 4; ++fi)
            #pragma unroll
            for (int fj = 0; fj < 4; ++fj)
                acc[fi][fj] = __builtin_amdgcn_mfma_f32_16x16x32_bf16(
                    af[fi], bfv[fj], acc[fi][fj], 0, 0, 0);
        __syncthreads();
    }

    const float scale = (EPI == 2) ? scaleP[bz] : 1.0f;
    #pragma unroll
    for (int fi = 0; fi < 4; ++fi) {
        #pragma unroll
        for (int fj = 0; fj < 4; ++fj) {
            v4f t = acc[fi][fj];
            int col = bn + wn + fj * 16 + fr;
            float bb = bp[col];
            int rbase = bm + wm + fi * 16 + (kh << 2);
            #pragma unroll
            for (int r = 0; r < 4; ++r) {
                float v = t[r] + bb;
                if constexpr (EPI == 1)
                    v = 0.5f * v * (1.0f + erff(v * 0.70710678118654752440f));
                if constexpr (EPI == 2)
                    v *= scale;
                size_t off = (size_t)bz * (size_t)cStride +
                             (size_t)(rbase + r) * N + col;
                if constexpr (EPI == 0)
                    ((float*)Cv)[off] = v;
                else
                    ((unsigned short*)Cv)[off] = f2b(v);
            }
        }
    }
}

// ---------------------------------------------------------------------------
// split-bf16 MFMA GEMM for U: C = Ahi@Bhi^T + Ahi@Blo^T + Alo@Bhi^T
//                                + bias1 + bias2  (fp32 out, ~fp32 accuracy)
// ---------------------------------------------------------------------------
__global__ __launch_bounds__(256)
void gemm_bf16_split(const unsigned short* __restrict__ Ahi,
                     const unsigned short* __restrict__ Alo,
                     const unsigned short* __restrict__ Bhi,
                     const unsigned short* __restrict__ Blo,
                     const float* __restrict__ bias1,
                     const float* __restrict__ bias2,
                     float* __restrict__ C, int N, int K)
{
    __shared__ __align__(16) unsigned short AsmH[128 * 32];
    __shared__ __align__(16) unsigned short AsmL[128 * 32];
    __shared__ __align__(16) unsigned short BsmH[128 * 32];
    __shared__ __align__(16) unsigned short BsmL[128 * 32];

    const int tid = threadIdx.x;
    const int wave = tid >> 6, lane = tid & 63;
    int bxs = blockIdx.x, bys = blockIdx.y;
    xcd_swizzle(bxs, bys);
    const int bm = bys * 128, bn = bxs * 128;
    const int wm = (wave >> 1) * 64, wn = (wave & 1) * 64;
    const int fr = lane & 15, kh = lane >> 4;

    const int lo0 = wave * 1024 + lane * 16;
    const int lo1 = 4096 + lo0;
    const int r0 = lo0 >> 6, q0 = (lo0 & 63) >> 1;
    const int r1 = lo1 >> 6, q1 = (lo1 & 63) >> 1;
    const unsigned short* ah0 = Ahi + (size_t)(bm + r0) * K + q0;
    const unsigned short* ah1 = Ahi + (size_t)(bm + r1) * K + q1;
    const unsigned short* al0 = Alo + (size_t)(bm + r0) * K + q0;
    const unsigned short* al1 = Alo + (size_t)(bm + r1) * K + q1;
    const unsigned short* bh0 = Bhi + (size_t)(bn + r0) * K + q0;
    const unsigned short* bh1 = Bhi + (size_t)(bn + r1) * K + q1;
    const unsigned short* bl0 = Blo + (size_t)(bn + r0) * K + q0;
    const unsigned short* bl1 = Blo + (size_t)(bn + r1) * K + q1;

    v4f acc[4][4];
    #pragma unroll
    for (int i = 0; i < 4; ++i)
        #pragma unroll
        for (int j = 0; j < 4; ++j) {
            acc[i][j][0] = 0.f; acc[i][j][1] = 0.f;
            acc[i][j][2] = 0.f; acc[i][j][3] = 0.f;
        }

    for (int k0 = 0; k0 < K; k0 += 32) {
        load_lds16(ah0 + k0, (char*)AsmH + wave * 1024);
        load_lds16(ah1 + k0, (char*)AsmH + 4096 + wave * 1024);
        load_lds16(al0 + k0, (char*)AsmL + wave * 1024);
        load_lds16(al1 + k0, (char*)AsmL + 4096 + wave * 1024);
        load_lds16(bh0 + k0, (char*)BsmH + wave * 1024);
        load_lds16(bh1 + k0, (char*)BsmH + 4096 + wave * 1024);
        load_lds16(bl0 + k0, (char*)BsmL + wave * 1024);
        load_lds16(bl1 + k0, (char*)BsmL + 4096 + wave * 1024);
        __syncthreads();

        v8s ahf[4], alf[4];
        #pragma unroll
        for (int f = 0; f < 4; ++f) {
            int ao = ((wm + f * 16 + fr) << 6) + (kh << 4);
            ahf[f] = *(const v8s*)((const char*)AsmH + ao);
            alf[f] = *(const v8s*)((const char*)AsmL + ao);
        }
        #pragma unroll
        for (int fj = 0; fj < 4; ++fj) {
            int bo = ((wn + fj * 16 + fr) << 6) + (kh << 4);
            v8s bh = *(const v8s*)((const char*)BsmH + bo);
            v8s bl = *(const v8s*)((const char*)BsmL + bo);
            #pragma unroll
            for (int fi = 0; fi < 4; ++fi) {
                acc[fi][fj] = __builtin_amdgcn_mfma_f32_16x16x32_bf16(
                    alf[fi], bh, acc[fi][fj], 0, 0, 0);
                acc[fi][fj] = __builtin_amdgcn_mfma_f32_16x16x32_bf16(
                    ahf[fi], bl, acc[fi][fj], 0, 0, 0);
                acc[fi][fj] = __builtin_amdgcn_mfma_f32_16x16x32_bf16(
                    ahf[fi], bh, acc[fi][fj], 0, 0, 0);
            }
        }
        __syncthreads();
    }

    #pragma unroll
    for (int fi = 0; fi < 4; ++fi) {
        #pragma unroll
        for (int fj = 0; fj < 4; ++fj) {
            v4f t = acc[fi][fj];
            int col = bn + wn + fj * 16 + fr;
            float bb = bias1[col] + bias2[col];
            int rbase = bm + wm + fi * 16 + (kh << 2);
            #pragma unroll
            for (int r = 0; r < 4; ++r)
                C[(size_t)(rbase + r) * N + col] = t[r] + bb;
        }
    }
}

// ---------------------------------------------------------------------------
extern "C" void kernel_launch(void* const* d_in, const int* in_sizes, int n_in,
                              void* d_out, int out_size, void* d_ws, size_t ws_size,
                              hipStream_t stream)
{
    const int*   tokens = (const int*)  d_in[0];
    const float* emb    = (const float*)d_in[1];
    const float* Wih    = (const float*)d_in[2];
    const float* bih    = (const float*)d_in[3];
    const float* Whh    = (const float*)d_in[4];
    const float* bhh    = (const float*)d_in[5];
    const float* Wg     = (const float*)d_in[6];
    const float* W1     = (const float*)d_in[7];
    const float* b1     = (const float*)d_in[8];
    const float* W2     = (const float*)d_in[9];
    const float* b2     = (const float*)d_in[10];
    const float* Wfc    = (const float*)d_in[11];
    const float* bfc    = (const float*)d_in[12];
    float* out = (float*)d_out;
    float* ws  = (float*)d_ws;

    // ws layout (float offsets), ~117.4 MB, aliased by lifetime:
    float*          U     = ws;                                   // 4,194,304
    float*          HS    = ws + 4194304;                         // 4,194,304
    unsigned short* HSbf  = (unsigned short*)(ws + 8388608);      // 2,097,152 fl
    float*          Ebase = ws + 10485760;                        // 8,388,608 fl (32MB)
    float*          Fbase = ws + 18874368;                        // 8,388,608 fl (32MB)
    unsigned short* Ybf   = (unsigned short*)(ws + 27262976);     // 2,097,152 fl
    float*          MEANX = ws + 29360128;                        // 4096
    float*          WGATE = ws + 29364224;                        // 4
    int*            IDX   = (int*)(ws + 29364228);                // 4
    // aliases (lifetimes disjoint in stream order):
    unsigned short* Xhi   = (unsigned short*)Ebase;               // 8MB, pre-RNN
    unsigned short* Xlo   = (unsigned short*)(Ebase + 2097152);   // 8MB, pre-RNN
    unsigned short* Whi   = (unsigned short*)(Ebase + 4194304);   // 2MB, pre-RNN
    unsigned short* Wlo   = (unsigned short*)(Ebase + 4718592);   // 2MB, pre-RNN
    unsigned long long* HPAIR = (unsigned long long*)Fbase;       // 64KB, RNN only
    unsigned short* W1T   = (unsigned short*)Ebase;               // 32MB, post-gate
    unsigned short* W2T   = (unsigned short*)Ebase;               // 32MB
    unsigned short* H1bf  = (unsigned short*)Fbase;               // 32MB
    unsigned short* Wfcbf = (unsigned short*)Ebase;               // 62.5MB spans E+F

    hipMemsetAsync(HPAIR, 0, 2 * 4096 * sizeof(unsigned long long), stream);

    // split-bf16 casts: X = emb[tokens], W = Wih (already N x K for A@B^T)
    split_cast<true ><<<BB * SS, 256, 0, stream>>>(emb, tokens, Xhi, Xlo);
    split_cast<false><<<DD, 256, 0, stream>>>(Wih, nullptr, Whi, Wlo);

    // U = X @ Wih^T + bih + bhh  (3-term split-bf16 MFMA, ~fp32-exact)
    gemm_bf16_split<<<dim3(DD / 128, (BB * SS) / 128, 1), 256, 0, stream>>>(
        Xhi, Xlo, Whi, Wlo, bih, bhh, U, DD, DD);

    // RNN scan (tagged-pair sync, single barrier/step, fused mean)
    rnn_kernel<<<64, 1024, 0, stream>>>(U, Whh, HS, HPAIR, MEANX);

    // gate (fp32 path)
    gate_kernel<<<1, 256, 0, stream>>>(MEANX, Wg, WGATE, IDX);

    // bf16 activations for MoE
    cast_kernel<<<1024, 256, 0, stream>>>(HS, HSbf, (long long)(BB * SS) * DD / 4);

    // W1T[z] = bf16(W1[idx[z]]^T)  [DFF][DD]   (clobbers Xhi/Xlo/Whi/Wlo: dead)
    transpose_cast<<<dim3(DFF / 32, DD / 32, BB), 256, 0, stream>>>(
        W1, IDX, W1T, DD, DFF, (long long)DD * DFF, (long long)DFF * DD);

    // H1bf = gelu(HSbf @ W1T^T + b1[e])  (bf16 out; clobbers HPAIR: dead)
    gemm_bf16<1><<<dim3(DFF / 128, SS / 128, BB), 256, 0, stream>>>(
        HSbf, W1T, b1, H1bf, DFF, DD,
        (long long)SS * DD, (long long)SS * DFF, (long long)DFF * DD,
        nullptr, IDX);

    // W2T[z] = bf16(W2[idx[z]]^T)  [DD][DFF]   (clobbers W1T: dead)
    transpose_cast<<<dim3(DD / 32, DFF / 32, BB), 256, 0, stream>>>(
        W2, IDX, W2T, DFF, DD, (long long)DFF * DD, (long long)DD * DFF);

    // Ybf = (H1bf @ W2T^T + b2[e]) * w  (bf16 out)
    gemm_bf16<2><<<dim3(DD / 128, SS / 128, BB), 256, 0, stream>>>(
        H1bf, W2T, b2, Ybf, DD, DFF,
        (long long)SS * DFF, (long long)SS * DD, (long long)DD * DFF,
        WGATE, IDX);

    // Wfc -> bf16 (clobbers W2T + H1bf: dead)
    cast_kernel<<<4096, 256, 0, stream>>>(Wfc, Wfcbf, (long long)VOC * DD / 4);

    // logits = Ybf @ Wfcbf^T + bfc  (fp32 out)
    gemm_bf16<0><<<dim3(VOC / 128, (BB * SS) / 128, 1), 256, 0, stream>>>(
        Ybf, Wfcbf, bfc, out, VOC, DD, 0, 0, 0, nullptr, nullptr);
}

// Round 6
// 2783.688 us; speedup vs baseline: 5.3878x; 1.0145x over previous
//
#include <hip/hip_runtime.h>
#include <hip/hip_bf16.h>
#include <math.h>

#define DD    1024
#define SS    1024
#define BB    4
#define EE    4
#define DFF   4096
#define VOC   32000

typedef __attribute__((ext_vector_type(8))) short v8s;   // 8 bf16 (4 VGPRs)
typedef __attribute__((ext_vector_type(4))) float v4f;   // MFMA accumulator

// fp32 -> bf16 (RNE)
__device__ __forceinline__ unsigned short f2b(float f) {
    unsigned u = __float_as_uint(f);
    unsigned r = (u + 0x7FFFu + ((u >> 16) & 1u)) >> 16;
    return (unsigned short)r;
}
__device__ __forceinline__ float b2f(unsigned short h) {
    return __uint_as_float((unsigned)h << 16);
}

// bijective XCD-aware block swizzle (m204): safe for any nwg
__device__ __forceinline__ void xcd_swizzle(int& bx, int& by) {
    int gx = gridDim.x;
    int nwg = gx * gridDim.y;
    int id = by * gx + bx;
    int q = nwg >> 3, r = nwg & 7;
    int xcd = id & 7, o = id >> 3;
    int swz = (xcd < r ? xcd * (q + 1) : r * (q + 1) + (xcd - r) * q) + o;
    bx = swz % gx; by = swz / gx;
}

// ---------------------------------------------------------------------------
// split-bf16 casts for the U GEMM (Ootomo 3-term): x = hi + lo, both bf16.
// ---------------------------------------------------------------------------
template<bool GATHER>
__global__ __launch_bounds__(256)
void split_cast(const float* __restrict__ src, const int* __restrict__ tokens,
                unsigned short* __restrict__ Xhi, unsigned short* __restrict__ Xlo)
{
    const int row = blockIdx.x;
    const float4* s;
    if constexpr (GATHER)
        s = (const float4*)(src + (size_t)tokens[row] * DD);
    else
        s = (const float4*)(src + (size_t)row * DD);
    const int c = threadIdx.x;          // 256 float4 per 1024-wide row
    float4 v = s[c];
    ushort4 hi, lo;
    hi.x = f2b(v.x); hi.y = f2b(v.y); hi.z = f2b(v.z); hi.w = f2b(v.w);
    lo.x = f2b(v.x - b2f(hi.x)); lo.y = f2b(v.y - b2f(hi.y));
    lo.z = f2b(v.z - b2f(hi.z)); lo.w = f2b(v.w - b2f(hi.w));
    ((ushort4*)Xhi)[(size_t)row * 256 + c] = hi;
    ((ushort4*)Xlo)[(size_t)row * 256 + c] = lo;
}

// ---------------------------------------------------------------------------
// Persistent RNN v6: batch-split sync groups. 64 blocks x 1024 threads;
// block (b = blk>>4, gg = blk&15) owns outputs d in [gg*64, gg*64+64) of
// batch b. Batches are INDEPENDENT chains: sync group = the 16 blocks of one
// batch; hpair[b][parity][1024] tagged pairs (val, step+1). Poll = ONE
// dwordx2 (8 B) per thread. Weights held in 16 NAMED float4 registers
// (R5's array version was demoted: VGPR_Count=52 < 64 -> per-step re-loads).
// Publish lanes write bf16 HSbf directly + fused mean. One barrier/step.
// ---------------------------------------------------------------------------
__global__ __launch_bounds__(1024)
void rnn_kernel(const float* __restrict__ U,
                const float* __restrict__ Whh,
                unsigned short* __restrict__ HSbf,
                unsigned long long* __restrict__ hpair,
                float* __restrict__ MEANX)
{
    __shared__ float hs_s[2][1088];       // [parity][k + (k>>6)*4 skew]

    const int tid = threadIdx.x;
    const int b  = blockIdx.x >> 4;       // batch
    const int gg = blockIdx.x & 15;       // dim group
    const int out = tid >> 4;             // 0..63
    const int chunk = tid & 15;           // 0..15
    const int d_own = gg * 64 + out;
    const bool is_res = (chunk == 0);

    const float4* wrow = (const float4*)(Whh + (size_t)d_own * DD + chunk * 64);
    float4 w00 = wrow[0],  w01 = wrow[1],  w02 = wrow[2],  w03 = wrow[3];
    float4 w04 = wrow[4],  w05 = wrow[5],  w06 = wrow[6],  w07 = wrow[7];
    float4 w08 = wrow[8],  w09 = wrow[9],  w10 = wrow[10], w11 = wrow[11];
    float4 w12 = wrow[12], w13 = wrow[13], w14 = wrow[14], w15 = wrow[15];

    const int sofs = tid + ((tid >> 6) << 2);     // scatter offset (skewed)
    const int rofs = chunk * 68;                  // read base (skewed)
    unsigned long long* hp_b = hpair + (size_t)b * 2048;

    float m_acc = 0.f;

    for (int t = 0; t < SS; ++t) {
        const int par = t & 1;
        float u_pre = 0.f;
        if (is_res)
            u_pre = U[((size_t)(b * SS + t)) * DD + d_own];

        if (t > 0) {
            const unsigned long long* pp = hp_b + (size_t)((t - 1) & 1) * 1024 + tid;
            uint2 q;
            const unsigned tg = (unsigned)t;
            for (;;) {
                asm volatile(
                    "global_load_dwordx2 %0, %1, off sc0 sc1\n\t"
                    "s_waitcnt vmcnt(0)"
                    : "=&v"(q) : "v"(pp) : "memory");
                if (q.y == tg) break;
                __builtin_amdgcn_s_sleep(1);
            }
            hs_s[par][sofs] = __uint_as_float(q.x);
        }
        __syncthreads();

        float acc = 0.f;
        if (t > 0) {
            const float* rb = &hs_s[par][rofs];
            float4 h;
            h = *(const float4*)(rb +  0); acc += w00.x*h.x + w00.y*h.y + w00.z*h.z + w00.w*h.w;
            h = *(const float4*)(rb +  4); acc += w01.x*h.x + w01.y*h.y + w01.z*h.z + w01.w*h.w;
            h = *(const float4*)(rb +  8); acc += w02.x*h.x + w02.y*h.y + w02.z*h.z + w02.w*h.w;
            h = *(const float4*)(rb + 12); acc += w03.x*h.x + w03.y*h.y + w03.z*h.z + w03.w*h.w;
            h = *(const float4*)(rb + 16); acc += w04.x*h.x + w04.y*h.y + w04.z*h.z + w04.w*h.w;
            h = *(const float4*)(rb + 20); acc += w05.x*h.x + w05.y*h.y + w05.z*h.z + w05.w*h.w;
            h = *(const float4*)(rb + 24); acc += w06.x*h.x + w06.y*h.y + w06.z*h.z + w06.w*h.w;
            h = *(const float4*)(rb + 28); acc += w07.x*h.x + w07.y*h.y + w07.z*h.z + w07.w*h.w;
            h = *(const float4*)(rb + 32); acc += w08.x*h.x + w08.y*h.y + w08.z*h.z + w08.w*h.w;
            h = *(const float4*)(rb + 36); acc += w09.x*h.x + w09.y*h.y + w09.z*h.z + w09.w*h.w;
            h = *(const float4*)(rb + 40); acc += w10.x*h.x + w10.y*h.y + w10.z*h.z + w10.w*h.w;
            h = *(const float4*)(rb + 44); acc += w11.x*h.x + w11.y*h.y + w11.z*h.z + w11.w*h.w;
            h = *(const float4*)(rb + 48); acc += w12.x*h.x + w12.y*h.y + w12.z*h.z + w12.w*h.w;
            h = *(const float4*)(rb + 52); acc += w13.x*h.x + w13.y*h.y + w13.z*h.z + w13.w*h.w;
            h = *(const float4*)(rb + 56); acc += w14.x*h.x + w14.y*h.y + w14.z*h.z + w14.w*h.w;
            h = *(const float4*)(rb + 60); acc += w15.x*h.x + w15.y*h.y + w15.z*h.z + w15.w*h.w;
            acc += __shfl_xor(acc, 1);
            acc += __shfl_xor(acc, 2);
            acc += __shfl_xor(acc, 4);
            acc += __shfl_xor(acc, 8);
        }

        if (is_res) {
            float h = tanhf(u_pre + acc);
            HSbf[((size_t)(b * SS + t)) * DD + d_own] = f2b(h);
            m_acc += h;
            unsigned long long pk =
                ((unsigned long long)(unsigned)(t + 1) << 32) |
                (unsigned long long)__float_as_uint(h);
            __hip_atomic_store(hp_b + (size_t)par * 1024 + d_own, pk,
                               __ATOMIC_RELAXED, __HIP_MEMORY_SCOPE_AGENT);
        }
    }

    if (is_res)
        MEANX[b * DD + d_own] = m_acc * (1.0f / (float)SS);
}

// gates = softmax(MEANX @ Wg^T); top-1 weight + index per batch. 1 block.
__global__ __launch_bounds__(256)
void gate_kernel(const float* __restrict__ MEANX, const float* __restrict__ Wg,
                 float* __restrict__ WGATE, int* __restrict__ IDX)
{
    __shared__ float sc[4][4];
    const int tid = threadIdx.x;
    const int p = tid >> 4, l = tid & 15;
    const int b = p >> 2, e = p & 3;
    float acc = 0.f;
    for (int j = 0; j < 64; ++j)
        acc += MEANX[b * DD + l * 64 + j] * Wg[e * DD + l * 64 + j];
    acc += __shfl_xor(acc, 1); acc += __shfl_xor(acc, 2);
    acc += __shfl_xor(acc, 4); acc += __shfl_xor(acc, 8);
    if (l == 0) sc[b][e] = acc;
    __syncthreads();
    if (tid < 4) {
        float s0 = sc[tid][0], s1 = sc[tid][1], s2 = sc[tid][2], s3 = sc[tid][3];
        float mx = fmaxf(fmaxf(s0, s1), fmaxf(s2, s3));
        float e0 = expf(s0 - mx), e1 = expf(s1 - mx);
        float e2 = expf(s2 - mx), e3 = expf(s3 - mx);
        float inv = 1.0f / (e0 + e1 + e2 + e3);
        float pr[4] = {e0 * inv, e1 * inv, e2 * inv, e3 * inv};
        int arg = 0; float best = pr[0];
        if (pr[1] > best) { best = pr[1]; arg = 1; }
        if (pr[2] > best) { best = pr[2]; arg = 2; }
        if (pr[3] > best) { best = pr[3]; arg = 3; }
        WGATE[tid] = best;
        IDX[tid] = arg;
    }
}

// fp32 -> bf16 cast, float4-granular, grid-stride
__global__ __launch_bounds__(256)
void cast_kernel(const float* __restrict__ in, unsigned short* __restrict__ out,
                 long long n4)
{
    long long stride = (long long)gridDim.x * blockDim.x;
    for (long long i = (long long)blockIdx.x * blockDim.x + threadIdx.x;
         i < n4; i += stride) {
        float4 v = ((const float4*)in)[i];
        ushort4 o;
        o.x = f2b(v.x); o.y = f2b(v.y); o.z = f2b(v.z); o.w = f2b(v.w);
        ((ushort4*)out)[i] = o;
    }
}

// transpose-cast: src fp32 [R][C] (expert expIdx[z]) -> dst bf16 [C][R] (z)
__global__ __launch_bounds__(256)
void transpose_cast(const float* __restrict__ src, const int* __restrict__ expIdx,
                    unsigned short* __restrict__ dst, int R, int C,
                    long long srcExpStride, long long dstZStride)
{
    __shared__ float tbuf[32][33];
    const int tid = threadIdx.x;
    const int z = blockIdx.z;
    const float* S = src + (long long)expIdx[z] * srcExpStride;
    unsigned short* D = dst + (long long)z * dstZStride;
    const int r0 = blockIdx.y * 32, c0 = blockIdx.x * 32;
    const int tr = tid >> 3, tc = (tid & 7) * 4;
    float4 v = *(const float4*)(S + (long long)(r0 + tr) * C + c0 + tc);
    tbuf[tr][tc + 0] = v.x; tbuf[tr][tc + 1] = v.y;
    tbuf[tr][tc + 2] = v.z; tbuf[tr][tc + 3] = v.w;
    __syncthreads();
    ushort4 o;
    o.x = f2b(tbuf[tc + 0][tr]); o.y = f2b(tbuf[tc + 1][tr]);
    o.z = f2b(tbuf[tc + 2][tr]); o.w = f2b(tbuf[tc + 3][tr]);
    *(ushort4*)(D + (long long)(c0 + tr) * R + r0 + tc) = o;
}

// ---------------------------------------------------------------------------
// bf16 MFMA GEMM (m97 structure): C = A[M][K] @ Bt[N][K]^T, fused epilogues.
// EPI 0: +bias -> fp32 | EPI 1: gelu(x+bias[e]) -> bf16 | EPI 2: (x+bias[e])*w -> bf16
// ---------------------------------------------------------------------------
__device__ __forceinline__ void load_lds16(const void* g, void* l) {
    __builtin_amdgcn_global_load_lds(
        (const __attribute__((address_space(1))) unsigned int*)g,
        (__attribute__((address_space(3))) unsigned int*)l, 16, 0, 0);
}

template<int EPI>
__global__ __launch_bounds__(256)
void gemm_bf16(const unsigned short* __restrict__ A,
               const unsigned short* __restrict__ Bt,
               const float* __restrict__ bias,
               void* __restrict__ Cv,
               int N, int K,
               long long aStride, long long cStride, long long btStride,
               const float* __restrict__ scaleP, const int* __restrict__ expIdx)
{
    __shared__ __align__(16) unsigned short Asm[128 * 32];
    __shared__ __align__(16) unsigned short Bsm[128 * 32];

    const int tid = threadIdx.x;
    const int wave = tid >> 6, lane = tid & 63;
    int bxs = blockIdx.x, bys = blockIdx.y;
    xcd_swizzle(bxs, bys);
    const int bm = bys * 128, bn = bxs * 128;
    const int bz = blockIdx.z;
    const int wm = (wave >> 1) * 64, wn = (wave & 1) * 64;
    const int fr = lane & 15, kh = lane >> 4;

    const unsigned short* Az  = A  + (long long)bz * aStride;
    const unsigned short* Btz = Bt + (long long)bz * btStride;
    const float* bp = bias + (expIdx ? (long long)expIdx[bz] * N : 0);

    const int lo0 = wave * 1024 + lane * 16;
    const int lo1 = 4096 + lo0;
    const int r0 = lo0 >> 6, q0 = (lo0 & 63) >> 1;
    const int r1 = lo1 >> 6, q1 = (lo1 & 63) >> 1;
    const unsigned short* a0 = Az  + (size_t)(bm + r0) * K + q0;
    const unsigned short* a1 = Az  + (size_t)(bm + r1) * K + q1;
    const unsigned short* b0 = Btz + (size_t)(bn + r0) * K + q0;
    const unsigned short* b1 = Btz + (size_t)(bn + r1) * K + q1;

    v4f acc[4][4];
    #pragma unroll
    for (int i = 0; i < 4; ++i)
        #pragma unroll
        for (int j = 0; j < 4; ++j) {
            acc[i][j][0] = 0.f; acc[i][j][1] = 0.f;
            acc[i][j][2] = 0.f; acc[i][j][3] = 0.f;
        }

    for (int k0 = 0; k0 < K; k0 += 32) {
        load_lds16(a0 + k0, (char*)Asm + wave * 1024);
        load_lds16(a1 + k0, (char*)Asm + 4096 + wave * 1024);
        load_lds16(b0 + k0, (char*)Bsm + wave * 1024);
        load_lds16(b1 + k0, (char*)Bsm + 4096 + wave * 1024);
        __syncthreads();

        v8s af[4], bfv[4];
        #pragma unroll
        for (int f = 0; f < 4; ++f) {
            af[f]  = *(const v8s*)((const char*)Asm + ((wm + f * 16 + fr) << 6) + (kh << 4));
            bfv[f] = *(const v8s*)((const char*)Bsm + ((wn + f * 16 + fr) << 6) + (kh << 4));
        }
        #pragma unroll
        for (int fi = 0; fi < 4; ++fi)
            #pragma unroll
            for (int fj = 0; fj < 4; ++fj)
                acc[fi][fj] = __builtin_amdgcn_mfma_f32_16x16x32_bf16(
                    af[fi], bfv[fj], acc[fi][fj], 0, 0, 0);
        __syncthreads();
    }

    const float scale = (EPI == 2) ? scaleP[bz] : 1.0f;
    #pragma unroll
    for (int fi = 0; fi < 4; ++fi) {
        #pragma unroll
        for (int fj = 0; fj < 4; ++fj) {
            v4f t = acc[fi][fj];
            int col = bn + wn + fj * 16 + fr;
            float bb = bp[col];
            int rbase = bm + wm + fi * 16 + (kh << 2);
            #pragma unroll
            for (int r = 0; r < 4; ++r) {
                float v = t[r] + bb;
                if constexpr (EPI == 1)
                    v = 0.5f * v * (1.0f + erff(v * 0.70710678118654752440f));
                if constexpr (EPI == 2)
                    v *= scale;
                size_t off = (size_t)bz * (size_t)cStride +
                             (size_t)(rbase + r) * N + col;
                if constexpr (EPI == 0)
                    ((float*)Cv)[off] = v;
                else
                    ((unsigned short*)Cv)[off] = f2b(v);
            }
        }
    }
}

// ---------------------------------------------------------------------------
// split-bf16 MFMA GEMM for U: C = Ahi@Bhi^T + Ahi@Blo^T + Alo@Bhi^T
//                                + bias1 + bias2  (fp32 out, ~fp32 accuracy)
// ---------------------------------------------------------------------------
__global__ __launch_bounds__(256)
void gemm_bf16_split(const unsigned short* __restrict__ Ahi,
                     const unsigned short* __restrict__ Alo,
                     const unsigned short* __restrict__ Bhi,
                     const unsigned short* __restrict__ Blo,
                     const float* __restrict__ bias1,
                     const float* __restrict__ bias2,
                     float* __restrict__ C, int N, int K)
{
    __shared__ __align__(16) unsigned short AsmH[128 * 32];
    __shared__ __align__(16) unsigned short AsmL[128 * 32];
    __shared__ __align__(16) unsigned short BsmH[128 * 32];
    __shared__ __align__(16) unsigned short BsmL[128 * 32];

    const int tid = threadIdx.x;
    const int wave = tid >> 6, lane = tid & 63;
    int bxs = blockIdx.x, bys = blockIdx.y;
    xcd_swizzle(bxs, bys);
    const int bm = bys * 128, bn = bxs * 128;
    const int wm = (wave >> 1) * 64, wn = (wave & 1) * 64;
    const int fr = lane & 15, kh = lane >> 4;

    const int lo0 = wave * 1024 + lane * 16;
    const int lo1 = 4096 + lo0;
    const int r0 = lo0 >> 6, q0 = (lo0 & 63) >> 1;
    const int r1 = lo1 >> 6, q1 = (lo1 & 63) >> 1;
    const unsigned short* ah0 = Ahi + (size_t)(bm + r0) * K + q0;
    const unsigned short* ah1 = Ahi + (size_t)(bm + r1) * K + q1;
    const unsigned short* al0 = Alo + (size_t)(bm + r0) * K + q0;
    const unsigned short* al1 = Alo + (size_t)(bm + r1) * K + q1;
    const unsigned short* bh0 = Bhi + (size_t)(bn + r0) * K + q0;
    const unsigned short* bh1 = Bhi + (size_t)(bn + r1) * K + q1;
    const unsigned short* bl0 = Blo + (size_t)(bn + r0) * K + q0;
    const unsigned short* bl1 = Blo + (size_t)(bn + r1) * K + q1;

    v4f acc[4][4];
    #pragma unroll
    for (int i = 0; i < 4; ++i)
        #pragma unroll
        for (int j = 0; j < 4; ++j) {
            acc[i][j][0] = 0.f; acc[i][j][1] = 0.f;
            acc[i][j][2] = 0.f; acc[i][j][3] = 0.f;
        }

    for (int k0 = 0; k0 < K; k0 += 32) {
        load_lds16(ah0 + k0, (char*)AsmH + wave * 1024);
        load_lds16(ah1 + k0, (char*)AsmH + 4096 + wave * 1024);
        load_lds16(al0 + k0, (char*)AsmL + wave * 1024);
        load_lds16(al1 + k0, (char*)AsmL + 4096 + wave * 1024);
        load_lds16(bh0 + k0, (char*)BsmH + wave * 1024);
        load_lds16(bh1 + k0, (char*)BsmH + 4096 + wave * 1024);
        load_lds16(bl0 + k0, (char*)BsmL + wave * 1024);
        load_lds16(bl1 + k0, (char*)BsmL + 4096 + wave * 1024);
        __syncthreads();

        v8s ahf[4], alf[4];
        #pragma unroll
        for (int f = 0; f < 4; ++f) {
            int ao = ((wm + f * 16 + fr) << 6) + (kh << 4);
            ahf[f] = *(const v8s*)((const char*)AsmH + ao);
            alf[f] = *(const v8s*)((const char*)AsmL + ao);
        }
        #pragma unroll
        for (int fj = 0; fj < 4; ++fj) {
            int bo = ((wn + fj * 16 + fr) << 6) + (kh << 4);
            v8s bh = *(const v8s*)((const char*)BsmH + bo);
            v8s bl = *(const v8s*)((const char*)BsmL + bo);
            #pragma unroll
            for (int fi = 0; fi < 4; ++fi) {
                acc[fi][fj] = __builtin_amdgcn_mfma_f32_16x16x32_bf16(
                    alf[fi], bh, acc[fi][fj], 0, 0, 0);
                acc[fi][fj] = __builtin_amdgcn_mfma_f32_16x16x32_bf16(
                    ahf[fi], bl, acc[fi][fj], 0, 0, 0);
                acc[fi][fj] = __builtin_amdgcn_mfma_f32_16x16x32_bf16(
                    ahf[fi], bh, acc[fi][fj], 0, 0, 0);
            }
        }
        __syncthreads();
    }

    #pragma unroll
    for (int fi = 0; fi < 4; ++fi) {
        #pragma unroll
        for (int fj = 0; fj < 4; ++fj) {
            v4f t = acc[fi][fj];
            int col = bn + wn + fj * 16 + fr;
            float bb = bias1[col] + bias2[col];
            int rbase = bm + wm + fi * 16 + (kh << 2);
            #pragma unroll
            for (int r = 0; r < 4; ++r)
                C[(size_t)(rbase + r) * N + col] = t[r] + bb;
        }
    }
}

// ---------------------------------------------------------------------------
extern "C" void kernel_launch(void* const* d_in, const int* in_sizes, int n_in,
                              void* d_out, int out_size, void* d_ws, size_t ws_size,
                              hipStream_t stream)
{
    const int*   tokens = (const int*)  d_in[0];
    const float* emb    = (const float*)d_in[1];
    const float* Wih    = (const float*)d_in[2];
    const float* bih    = (const float*)d_in[3];
    const float* Whh    = (const float*)d_in[4];
    const float* bhh    = (const float*)d_in[5];
    const float* Wg     = (const float*)d_in[6];
    const float* W1     = (const float*)d_in[7];
    const float* b1     = (const float*)d_in[8];
    const float* W2     = (const float*)d_in[9];
    const float* b2     = (const float*)d_in[10];
    const float* Wfc    = (const float*)d_in[11];
    const float* bfc    = (const float*)d_in[12];
    float* out = (float*)d_out;
    float* ws  = (float*)d_ws;

    // ws layout (float offsets), ~117.4 MB, aliased by lifetime:
    float*          U     = ws;                                   // 4,194,304 fl
    float*          HSdead= ws + 4194304;                         // recycled
    unsigned short* HSbf  = (unsigned short*)(ws + 8388608);      // 2,097,152 fl
    float*          Ebase = ws + 10485760;                        // 8,388,608 fl (32MB)
    float*          Fbase = ws + 18874368;                        // 8,388,608 fl (32MB)
    unsigned short* Ybf   = (unsigned short*)(ws + 27262976);     // 2,097,152 fl
    float*          MEANX = ws + 29360128;                        // 4096
    float*          WGATE = ws + 29364224;                        // 4
    int*            IDX   = (int*)(ws + 29364228);                // 4
    // aliases (lifetimes disjoint in stream order):
    unsigned long long* HPAIR = (unsigned long long*)HSdead;      // 64 KB (BB*2*1024 pairs)
    unsigned short* Xhi   = (unsigned short*)Ebase;               // 8MB, pre-RNN
    unsigned short* Xlo   = (unsigned short*)(Ebase + 2097152);   // 8MB, pre-RNN
    unsigned short* Whi   = (unsigned short*)(Ebase + 4194304);   // 2MB, pre-RNN
    unsigned short* Wlo   = (unsigned short*)(Ebase + 4718592);   // 2MB, pre-RNN
    unsigned short* W1T   = (unsigned short*)Ebase;               // 32MB, post-gate
    unsigned short* W2T   = (unsigned short*)Ebase;               // 32MB
    unsigned short* H1bf  = (unsigned short*)Fbase;               // 32MB
    unsigned short* Wfcbf = (unsigned short*)Ebase;               // 62.5MB spans E+F

    hipMemsetAsync(HPAIR, 0, (size_t)BB * 2 * 1024 * sizeof(unsigned long long),
                   stream);

    // split-bf16 casts: X = emb[tokens], W = Wih (N x K for A@B^T)
    split_cast<true ><<<BB * SS, 256, 0, stream>>>(emb, tokens, Xhi, Xlo);
    split_cast<false><<<DD, 256, 0, stream>>>(Wih, nullptr, Whi, Wlo);

    // U = X @ Wih^T + bih + bhh  (3-term split-bf16 MFMA, ~fp32-exact)
    gemm_bf16_split<<<dim3(DD / 128, (BB * SS) / 128, 1), 256, 0, stream>>>(
        Xhi, Xlo, Whi, Wlo, bih, bhh, U, DD, DD);

    // RNN scan (batch-split tagged-pair sync; produces HSbf + MEANX directly)
    rnn_kernel<<<64, 1024, 0, stream>>>(U, Whh, HSbf, HPAIR, MEANX);

    // gate (fp32 path)
    gate_kernel<<<1, 256, 0, stream>>>(MEANX, Wg, WGATE, IDX);

    // W1T[z] = bf16(W1[idx[z]]^T)  [DFF][DD]   (clobbers Xhi/Xlo/Whi/Wlo: dead)
    transpose_cast<<<dim3(DFF / 32, DD / 32, BB), 256, 0, stream>>>(
        W1, IDX, W1T, DD, DFF, (long long)DD * DFF, (long long)DFF * DD);

    // H1bf = gelu(HSbf @ W1T^T + b1[e])  (bf16 out)
    gemm_bf16<1><<<dim3(DFF / 128, SS / 128, BB), 256, 0, stream>>>(
        HSbf, W1T, b1, H1bf, DFF, DD,
        (long long)SS * DD, (long long)SS * DFF, (long long)DFF * DD,
        nullptr, IDX);

    // W2T[z] = bf16(W2[idx[z]]^T)  [DD][DFF]   (clobbers W1T: dead)
    transpose_cast<<<dim3(DD / 32, DFF / 32, BB), 256, 0, stream>>>(
        W2, IDX, W2T, DFF, DD, (long long)DFF * DD, (long long)DD * DFF);

    // Ybf = (H1bf @ W2T^T + b2[e]) * w  (bf16 out)
    gemm_bf16<2><<<dim3(DD / 128, SS / 128, BB), 256, 0, stream>>>(
        H1bf, W2T, b2, Ybf, DD, DFF,
        (long long)SS * DFF, (long long)SS * DD, (long long)DD * DFF,
        WGATE, IDX);

    // Wfc -> bf16 (clobbers W2T + H1bf: dead)
    cast_kernel<<<4096, 256, 0, stream>>>(Wfc, Wfcbf, (long long)VOC * DD / 4);

    // logits = Ybf @ Wfcbf^T + bfc  (fp32 out)
    gemm_bf16<0><<<dim3(VOC / 128, (BB * SS) / 128, 1), 256, 0, stream>>>(
        Ybf, Wfcbf, bfc, out, VOC, DD, 0, 0, 0, nullptr, nullptr);
}

// Round 7
// 2767.053 us; speedup vs baseline: 5.4202x; 1.0060x over previous
//
#include <hip/hip_runtime.h>
#include <hip/hip_bf16.h>
#include <math.h>

#define DD    1024
#define SS    1024
#define BB    4
#define EE    4
#define DFF   4096
#define VOC   32000

typedef __attribute__((ext_vector_type(8))) short v8s;   // 8 bf16 (4 VGPRs)
typedef __attribute__((ext_vector_type(4))) float v4f;   // MFMA accumulator
typedef __attribute__((ext_vector_type(4))) float f32x4; // asm-friendly float4

// fp32 -> bf16 (RNE)
__device__ __forceinline__ unsigned short f2b(float f) {
    unsigned u = __float_as_uint(f);
    unsigned r = (u + 0x7FFFu + ((u >> 16) & 1u)) >> 16;
    return (unsigned short)r;
}
__device__ __forceinline__ float b2f(unsigned short h) {
    return __uint_as_float((unsigned)h << 16);
}

// bijective XCD-aware block swizzle (m204): safe for any nwg
__device__ __forceinline__ void xcd_swizzle(int& bx, int& by) {
    int gx = gridDim.x;
    int nwg = gx * gridDim.y;
    int id = by * gx + bx;
    int q = nwg >> 3, r = nwg & 7;
    int xcd = id & 7, o = id >> 3;
    int swz = (xcd < r ? xcd * (q + 1) : r * (q + 1) + (xcd - r) * q) + o;
    bx = swz % gx; by = swz / gx;
}

// ---------------------------------------------------------------------------
// split-bf16 casts for the U GEMM (Ootomo 3-term): x = hi + lo, both bf16.
// ---------------------------------------------------------------------------
template<bool GATHER>
__global__ __launch_bounds__(256)
void split_cast(const float* __restrict__ src, const int* __restrict__ tokens,
                unsigned short* __restrict__ Xhi, unsigned short* __restrict__ Xlo)
{
    const int row = blockIdx.x;
    const float4* s;
    if constexpr (GATHER)
        s = (const float4*)(src + (size_t)tokens[row] * DD);
    else
        s = (const float4*)(src + (size_t)row * DD);
    const int c = threadIdx.x;          // 256 float4 per 1024-wide row
    float4 v = s[c];
    ushort4 hi, lo;
    hi.x = f2b(v.x); hi.y = f2b(v.y); hi.z = f2b(v.z); hi.w = f2b(v.w);
    lo.x = f2b(v.x - b2f(hi.x)); lo.y = f2b(v.y - b2f(hi.y));
    lo.z = f2b(v.z - b2f(hi.z)); lo.w = f2b(v.w - b2f(hi.w));
    ((ushort4*)Xhi)[(size_t)row * 256 + c] = hi;
    ((ushort4*)Xlo)[(size_t)row * 256 + c] = lo;
}

// ---------------------------------------------------------------------------
// Persistent RNN v7: 256 blocks x 1024 threads, __launch_bounds__(1024,4)
// (min 4 waves/EU -> 128-VGPR cap; R5/R6's 64-cap forced Whh reloads = the
// 1.8 us/step L2 floor). Block (b = blk>>6, gg = blk&63) owns outputs
// [gg*16, gg*16+16) of batch b; WAVE w computes output gg*16+w; lane l holds
// Whh[d][l*16..+16) = 4 float4 loaded via asm volatile (cannot be sunk).
// LDS: one 1024-float h row per parity, skew stride 20 floats/16 -> uniform
// banks, no broadcast waste (64 distinct b128 addrs per instr).
// Tagged-pair sync unchanged: poll 1 pair (8 B) per thread, tag = step+1,
// parity double-buffer; single barrier/step (safety: barrier(t) separates
// scatter(t) writes from read(t); a thread reaching scatter(t+2) passed
// barrier(t+1), so all threads finished read(t)).
// ---------------------------------------------------------------------------
__global__ __launch_bounds__(1024, 4)
void rnn_kernel(const float* __restrict__ U,
                const float* __restrict__ Whh,
                unsigned short* __restrict__ HSbf,
                unsigned long long* __restrict__ hpair,
                float* __restrict__ MEANX)
{
    __shared__ __align__(16) float hs_s[2][1280];   // h[k] at k + (k>>4)*4

    const int tid = threadIdx.x;
    const int b  = blockIdx.x >> 6;       // batch
    const int gg = blockIdx.x & 63;       // output group
    const int w  = tid >> 6;              // wave = output within group
    const int l  = tid & 63;              // lane = 16-float K slice
    const int d_own = gg * 16 + w;
    const bool is_res = (l == 0);

    // Whh[d_own][l*16 .. +16) in 4 VGPR quads, pinned via asm volatile loads
    const float* wrow = Whh + (size_t)d_own * DD + l * 16;
    f32x4 w0, w1, w2, w3;
    asm volatile("global_load_dwordx4 %0, %1, off"           : "=v"(w0) : "v"(wrow) : "memory");
    asm volatile("global_load_dwordx4 %0, %1, off offset:16" : "=v"(w1) : "v"(wrow) : "memory");
    asm volatile("global_load_dwordx4 %0, %1, off offset:32" : "=v"(w2) : "v"(wrow) : "memory");
    asm volatile("global_load_dwordx4 %0, %1, off offset:48" : "=v"(w3) : "v"(wrow) : "memory");
    asm volatile("s_waitcnt vmcnt(0)" ::: "memory");

    const int sofs = tid + ((tid >> 4) << 2);     // scatter offset (skewed)
    const int rofs = l * 20;                      // read base (skewed slice)
    unsigned long long* hp_b = hpair + (size_t)b * 2048;

    float m_acc = 0.f;

    for (int t = 0; t < SS; ++t) {
        const int par = t & 1;
        float u_pre = 0.f;
        if (is_res)
            u_pre = U[((size_t)(b * SS + t)) * DD + d_own];

        if (t > 0) {
            const unsigned long long* pp = hp_b + (size_t)((t - 1) & 1) * 1024 + tid;
            uint2 q;
            const unsigned tg = (unsigned)t;
            for (;;) {
                asm volatile(
                    "global_load_dwordx2 %0, %1, off sc0 sc1\n\t"
                    "s_waitcnt vmcnt(0)"
                    : "=&v"(q) : "v"(pp) : "memory");
                if (q.y == tg) break;
                __builtin_amdgcn_s_sleep(1);
            }
            hs_s[par][sofs] = __uint_as_float(q.x);
        }
        __syncthreads();

        float acc = 0.f;
        if (t > 0) {
            const float* rb = &hs_s[par][rofs];
            f32x4 h0 = *(const f32x4*)(rb +  0);
            f32x4 h1 = *(const f32x4*)(rb +  4);
            f32x4 h2 = *(const f32x4*)(rb +  8);
            f32x4 h3 = *(const f32x4*)(rb + 12);
            acc  = w0.x*h0.x + w0.y*h0.y + w0.z*h0.z + w0.w*h0.w;
            acc += w1.x*h1.x + w1.y*h1.y + w1.z*h1.z + w1.w*h1.w;
            acc += w2.x*h2.x + w2.y*h2.y + w2.z*h2.z + w2.w*h2.w;
            acc += w3.x*h3.x + w3.y*h3.y + w3.z*h3.z + w3.w*h3.w;
            acc += __shfl_xor(acc, 1);
            acc += __shfl_xor(acc, 2);
            acc += __shfl_xor(acc, 4);
            acc += __shfl_xor(acc, 8);
            acc += __shfl_xor(acc, 16);
            acc += __shfl_xor(acc, 32);
        }

        if (is_res) {
            float h = tanhf(u_pre + acc);
            HSbf[((size_t)(b * SS + t)) * DD + d_own] = f2b(h);
            m_acc += h;
            unsigned long long pk =
                ((unsigned long long)(unsigned)(t + 1) << 32) |
                (unsigned long long)__float_as_uint(h);
            __hip_atomic_store(hp_b + (size_t)par * 1024 + d_own, pk,
                               __ATOMIC_RELAXED, __HIP_MEMORY_SCOPE_AGENT);
        }
    }

    if (is_res)
        MEANX[b * DD + d_own] = m_acc * (1.0f / (float)SS);
}

// gates = softmax(MEANX @ Wg^T); top-1 weight + index per batch. 1 block.
__global__ __launch_bounds__(256)
void gate_kernel(const float* __restrict__ MEANX, const float* __restrict__ Wg,
                 float* __restrict__ WGATE, int* __restrict__ IDX)
{
    __shared__ float sc[4][4];
    const int tid = threadIdx.x;
    const int p = tid >> 4, l = tid & 15;
    const int b = p >> 2, e = p & 3;
    float acc = 0.f;
    for (int j = 0; j < 64; ++j)
        acc += MEANX[b * DD + l * 64 + j] * Wg[e * DD + l * 64 + j];
    acc += __shfl_xor(acc, 1); acc += __shfl_xor(acc, 2);
    acc += __shfl_xor(acc, 4); acc += __shfl_xor(acc, 8);
    if (l == 0) sc[b][e] = acc;
    __syncthreads();
    if (tid < 4) {
        float s0 = sc[tid][0], s1 = sc[tid][1], s2 = sc[tid][2], s3 = sc[tid][3];
        float mx = fmaxf(fmaxf(s0, s1), fmaxf(s2, s3));
        float e0 = expf(s0 - mx), e1 = expf(s1 - mx);
        float e2 = expf(s2 - mx), e3 = expf(s3 - mx);
        float inv = 1.0f / (e0 + e1 + e2 + e3);
        float pr[4] = {e0 * inv, e1 * inv, e2 * inv, e3 * inv};
        int arg = 0; float best = pr[0];
        if (pr[1] > best) { best = pr[1]; arg = 1; }
        if (pr[2] > best) { best = pr[2]; arg = 2; }
        if (pr[3] > best) { best = pr[3]; arg = 3; }
        WGATE[tid] = best;
        IDX[tid] = arg;
    }
}

// fp32 -> bf16 cast, float4-granular, grid-stride
__global__ __launch_bounds__(256)
void cast_kernel(const float* __restrict__ in, unsigned short* __restrict__ out,
                 long long n4)
{
    long long stride = (long long)gridDim.x * blockDim.x;
    for (long long i = (long long)blockIdx.x * blockDim.x + threadIdx.x;
         i < n4; i += stride) {
        float4 v = ((const float4*)in)[i];
        ushort4 o;
        o.x = f2b(v.x); o.y = f2b(v.y); o.z = f2b(v.z); o.w = f2b(v.w);
        ((ushort4*)out)[i] = o;
    }
}

// transpose-cast: src fp32 [R][C] (expert expIdx[z]) -> dst bf16 [C][R] (z)
__global__ __launch_bounds__(256)
void transpose_cast(const float* __restrict__ src, const int* __restrict__ expIdx,
                    unsigned short* __restrict__ dst, int R, int C,
                    long long srcExpStride, long long dstZStride)
{
    __shared__ float tbuf[32][33];
    const int tid = threadIdx.x;
    const int z = blockIdx.z;
    const float* S = src + (long long)expIdx[z] * srcExpStride;
    unsigned short* D = dst + (long long)z * dstZStride;
    const int r0 = blockIdx.y * 32, c0 = blockIdx.x * 32;
    const int tr = tid >> 3, tc = (tid & 7) * 4;
    float4 v = *(const float4*)(S + (long long)(r0 + tr) * C + c0 + tc);
    tbuf[tr][tc + 0] = v.x; tbuf[tr][tc + 1] = v.y;
    tbuf[tr][tc + 2] = v.z; tbuf[tr][tc + 3] = v.w;
    __syncthreads();
    ushort4 o;
    o.x = f2b(tbuf[tc + 0][tr]); o.y = f2b(tbuf[tc + 1][tr]);
    o.z = f2b(tbuf[tc + 2][tr]); o.w = f2b(tbuf[tc + 3][tr]);
    *(ushort4*)(D + (long long)(c0 + tr) * R + r0 + tc) = o;
}

// ---------------------------------------------------------------------------
// bf16 MFMA GEMM (m97 structure): C = A[M][K] @ Bt[N][K]^T, fused epilogues.
// EPI 0: +bias -> fp32 | EPI 1: gelu(x+bias[e]) -> bf16 | EPI 2: (x+bias[e])*w -> bf16
// ---------------------------------------------------------------------------
__device__ __forceinline__ void load_lds16(const void* g, void* l) {
    __builtin_amdgcn_global_load_lds(
        (const __attribute__((address_space(1))) unsigned int*)g,
        (__attribute__((address_space(3))) unsigned int*)l, 16, 0, 0);
}

template<int EPI>
__global__ __launch_bounds__(256)
void gemm_bf16(const unsigned short* __restrict__ A,
               const unsigned short* __restrict__ Bt,
               const float* __restrict__ bias,
               void* __restrict__ Cv,
               int N, int K,
               long long aStride, long long cStride, long long btStride,
               const float* __restrict__ scaleP, const int* __restrict__ expIdx)
{
    __shared__ __align__(16) unsigned short Asm[128 * 32];
    __shared__ __align__(16) unsigned short Bsm[128 * 32];

    const int tid = threadIdx.x;
    const int wave = tid >> 6, lane = tid & 63;
    int bxs = blockIdx.x, bys = blockIdx.y;
    xcd_swizzle(bxs, bys);
    const int bm = bys * 128, bn = bxs * 128;
    const int bz = blockIdx.z;
    const int wm = (wave >> 1) * 64, wn = (wave & 1) * 64;
    const int fr = lane & 15, kh = lane >> 4;

    const unsigned short* Az  = A  + (long long)bz * aStride;
    const unsigned short* Btz = Bt + (long long)bz * btStride;
    const float* bp = bias + (expIdx ? (long long)expIdx[bz] * N : 0);

    const int lo0 = wave * 1024 + lane * 16;
    const int lo1 = 4096 + lo0;
    const int r0 = lo0 >> 6, q0 = (lo0 & 63) >> 1;
    const int r1 = lo1 >> 6, q1 = (lo1 & 63) >> 1;
    const unsigned short* a0 = Az  + (size_t)(bm + r0) * K + q0;
    const unsigned short* a1 = Az  + (size_t)(bm + r1) * K + q1;
    const unsigned short* b0 = Btz + (size_t)(bn + r0) * K + q0;
    const unsigned short* b1 = Btz + (size_t)(bn + r1) * K + q1;

    v4f acc[4][4];
    #pragma unroll
    for (int i = 0; i < 4; ++i)
        #pragma unroll
        for (int j = 0; j < 4; ++j) {
            acc[i][j][0] = 0.f; acc[i][j][1] = 0.f;
            acc[i][j][2] = 0.f; acc[i][j][3] = 0.f;
        }

    for (int k0 = 0; k0 < K; k0 += 32) {
        load_lds16(a0 + k0, (char*)Asm + wave * 1024);
        load_lds16(a1 + k0, (char*)Asm + 4096 + wave * 1024);
        load_lds16(b0 + k0, (char*)Bsm + wave * 1024);
        load_lds16(b1 + k0, (char*)Bsm + 4096 + wave * 1024);
        __syncthreads();

        v8s af[4], bfv[4];
        #pragma unroll
        for (int f = 0; f < 4; ++f) {
            af[f]  = *(const v8s*)((const char*)Asm + ((wm + f * 16 + fr) << 6) + (kh << 4));
            bfv[f] = *(const v8s*)((const char*)Bsm + ((wn + f * 16 + fr) << 6) + (kh << 4));
        }
        #pragma unroll
        for (int fi = 0; fi < 4; ++fi)
            #pragma unroll
            for (int fj = 0; fj < 4; ++fj)
                acc[fi][fj] = __builtin_amdgcn_mfma_f32_16x16x32_bf16(
                    af[fi], bfv[fj], acc[fi][fj], 0, 0, 0);
        __syncthreads();
    }

    const float scale = (EPI == 2) ? scaleP[bz] : 1.0f;
    #pragma unroll
    for (int fi = 0; fi < 4; ++fi) {
        #pragma unroll
        for (int fj = 0; fj < 4; ++fj) {
            v4f t = acc[fi][fj];
            int col = bn + wn + fj * 16 + fr;
            float bb = bp[col];
            int rbase = bm + wm + fi * 16 + (kh << 2);
            #pragma unroll
            for (int r = 0; r < 4; ++r) {
                float v = t[r] + bb;
                if constexpr (EPI == 1)
                    v = 0.5f * v * (1.0f + erff(v * 0.70710678118654752440f));
                if constexpr (EPI == 2)
                    v *= scale;
                size_t off = (size_t)bz * (size_t)cStride +
                             (size_t)(rbase + r) * N + col;
                if constexpr (EPI == 0)
                    ((float*)Cv)[off] = v;
                else
                    ((unsigned short*)Cv)[off] = f2b(v);
            }
        }
    }
}

// ---------------------------------------------------------------------------
// split-bf16 MFMA GEMM for U: C = Ahi@Bhi^T + Ahi@Blo^T + Alo@Bhi^T
//                                + bias1 + bias2  (fp32 out, ~fp32 accuracy)
// ---------------------------------------------------------------------------
__global__ __launch_bounds__(256)
void gemm_bf16_split(const unsigned short* __restrict__ Ahi,
                     const unsigned short* __restrict__ Alo,
                     const unsigned short* __restrict__ Bhi,
                     const unsigned short* __restrict__ Blo,
                     const float* __restrict__ bias1,
                     const float* __restrict__ bias2,
                     float* __restrict__ C, int N, int K)
{
    __shared__ __align__(16) unsigned short AsmH[128 * 32];
    __shared__ __align__(16) unsigned short AsmL[128 * 32];
    __shared__ __align__(16) unsigned short BsmH[128 * 32];
    __shared__ __align__(16) unsigned short BsmL[128 * 32];

    const int tid = threadIdx.x;
    const int wave = tid >> 6, lane = tid & 63;
    int bxs = blockIdx.x, bys = blockIdx.y;
    xcd_swizzle(bxs, bys);
    const int bm = bys * 128, bn = bxs * 128;
    const int wm = (wave >> 1) * 64, wn = (wave & 1) * 64;
    const int fr = lane & 15, kh = lane >> 4;

    const int lo0 = wave * 1024 + lane * 16;
    const int lo1 = 4096 + lo0;
    const int r0 = lo0 >> 6, q0 = (lo0 & 63) >> 1;
    const int r1 = lo1 >> 6, q1 = (lo1 & 63) >> 1;
    const unsigned short* ah0 = Ahi + (size_t)(bm + r0) * K + q0;
    const unsigned short* ah1 = Ahi + (size_t)(bm + r1) * K + q1;
    const unsigned short* al0 = Alo + (size_t)(bm + r0) * K + q0;
    const unsigned short* al1 = Alo + (size_t)(bm + r1) * K + q1;
    const unsigned short* bh0 = Bhi + (size_t)(bn + r0) * K + q0;
    const unsigned short* bh1 = Bhi + (size_t)(bn + r1) * K + q1;
    const unsigned short* bl0 = Blo + (size_t)(bn + r0) * K + q0;
    const unsigned short* bl1 = Blo + (size_t)(bn + r1) * K + q1;

    v4f acc[4][4];
    #pragma unroll
    for (int i = 0; i < 4; ++i)
        #pragma unroll
        for (int j = 0; j < 4; ++j) {
            acc[i][j][0] = 0.f; acc[i][j][1] = 0.f;
            acc[i][j][2] = 0.f; acc[i][j][3] = 0.f;
        }

    for (int k0 = 0; k0 < K; k0 += 32) {
        load_lds16(ah0 + k0, (char*)AsmH + wave * 1024);
        load_lds16(ah1 + k0, (char*)AsmH + 4096 + wave * 1024);
        load_lds16(al0 + k0, (char*)AsmL + wave * 1024);
        load_lds16(al1 + k0, (char*)AsmL + 4096 + wave * 1024);
        load_lds16(bh0 + k0, (char*)BsmH + wave * 1024);
        load_lds16(bh1 + k0, (char*)BsmH + 4096 + wave * 1024);
        load_lds16(bl0 + k0, (char*)BsmL + wave * 1024);
        load_lds16(bl1 + k0, (char*)BsmL + 4096 + wave * 1024);
        __syncthreads();

        v8s ahf[4], alf[4];
        #pragma unroll
        for (int f = 0; f < 4; ++f) {
            int ao = ((wm + f * 16 + fr) << 6) + (kh << 4);
            ahf[f] = *(const v8s*)((const char*)AsmH + ao);
            alf[f] = *(const v8s*)((const char*)AsmL + ao);
        }
        #pragma unroll
        for (int fj = 0; fj < 4; ++fj) {
            int bo = ((wn + fj * 16 + fr) << 6) + (kh << 4);
            v8s bh = *(const v8s*)((const char*)BsmH + bo);
            v8s bl = *(const v8s*)((const char*)BsmL + bo);
            #pragma unroll
            for (int fi = 0; fi < 4; ++fi) {
                acc[fi][fj] = __builtin_amdgcn_mfma_f32_16x16x32_bf16(
                    alf[fi], bh, acc[fi][fj], 0, 0, 0);
                acc[fi][fj] = __builtin_amdgcn_mfma_f32_16x16x32_bf16(
                    ahf[fi], bl, acc[fi][fj], 0, 0, 0);
                acc[fi][fj] = __builtin_amdgcn_mfma_f32_16x16x32_bf16(
                    ahf[fi], bh, acc[fi][fj], 0, 0, 0);
            }
        }
        __syncthreads();
    }

    #pragma unroll
    for (int fi = 0; fi < 4; ++fi) {
        #pragma unroll
        for (int fj = 0; fj < 4; ++fj) {
            v4f t = acc[fi][fj];
            int col = bn + wn + fj * 16 + fr;
            float bb = bias1[col] + bias2[col];
            int rbase = bm + wm + fi * 16 + (kh << 2);
            #pragma unroll
            for (int r = 0; r < 4; ++r)
                C[(size_t)(rbase + r) * N + col] = t[r] + bb;
        }
    }
}

// ---------------------------------------------------------------------------
extern "C" void kernel_launch(void* const* d_in, const int* in_sizes, int n_in,
                              void* d_out, int out_size, void* d_ws, size_t ws_size,
                              hipStream_t stream)
{
    const int*   tokens = (const int*)  d_in[0];
    const float* emb    = (const float*)d_in[1];
    const float* Wih    = (const float*)d_in[2];
    const float* bih    = (const float*)d_in[3];
    const float* Whh    = (const float*)d_in[4];
    const float* bhh    = (const float*)d_in[5];
    const float* Wg     = (const float*)d_in[6];
    const float* W1     = (const float*)d_in[7];
    const float* b1     = (const float*)d_in[8];
    const float* W2     = (const float*)d_in[9];
    const float* b2     = (const float*)d_in[10];
    const float* Wfc    = (const float*)d_in[11];
    const float* bfc    = (const float*)d_in[12];
    float* out = (float*)d_out;
    float* ws  = (float*)d_ws;

    // ws layout (float offsets), ~117.4 MB, aliased by lifetime:
    float*          U     = ws;                                   // 4,194,304 fl
    float*          HSdead= ws + 4194304;                         // recycled
    unsigned short* HSbf  = (unsigned short*)(ws + 8388608);      // 2,097,152 fl
    float*          Ebase = ws + 10485760;                        // 8,388,608 fl (32MB)
    float*          Fbase = ws + 18874368;                        // 8,388,608 fl (32MB)
    unsigned short* Ybf   = (unsigned short*)(ws + 27262976);     // 2,097,152 fl
    float*          MEANX = ws + 29360128;                        // 4096
    float*          WGATE = ws + 29364224;                        // 4
    int*            IDX   = (int*)(ws + 29364228);                // 4
    // aliases (lifetimes disjoint in stream order):
    unsigned long long* HPAIR = (unsigned long long*)HSdead;      // 64 KB (BB*2*1024 pairs)
    unsigned short* Xhi   = (unsigned short*)Ebase;               // 8MB, pre-RNN
    unsigned short* Xlo   = (unsigned short*)(Ebase + 2097152);   // 8MB, pre-RNN
    unsigned short* Whi   = (unsigned short*)(Ebase + 4194304);   // 2MB, pre-RNN
    unsigned short* Wlo   = (unsigned short*)(Ebase + 4718592);   // 2MB, pre-RNN
    unsigned short* W1T   = (unsigned short*)Ebase;               // 32MB, post-gate
    unsigned short* W2T   = (unsigned short*)Ebase;               // 32MB
    unsigned short* H1bf  = (unsigned short*)Fbase;               // 32MB
    unsigned short* Wfcbf = (unsigned short*)Ebase;               // 62.5MB spans E+F

    hipMemsetAsync(HPAIR, 0, (size_t)BB * 2 * 1024 * sizeof(unsigned long long),
                   stream);

    // split-bf16 casts: X = emb[tokens], W = Wih (N x K for A@B^T)
    split_cast<true ><<<BB * SS, 256, 0, stream>>>(emb, tokens, Xhi, Xlo);
    split_cast<false><<<DD, 256, 0, stream>>>(Wih, nullptr, Whi, Wlo);

    // U = X @ Wih^T + bih + bhh  (3-term split-bf16 MFMA, ~fp32-exact)
    gemm_bf16_split<<<dim3(DD / 128, (BB * SS) / 128, 1), 256, 0, stream>>>(
        Xhi, Xlo, Whi, Wlo, bih, bhh, U, DD, DD);

    // RNN scan (256-block wave-per-output; produces HSbf + MEANX directly)
    rnn_kernel<<<256, 1024, 0, stream>>>(U, Whh, HSbf, HPAIR, MEANX);

    // gate (fp32 path)
    gate_kernel<<<1, 256, 0, stream>>>(MEANX, Wg, WGATE, IDX);

    // W1T[z] = bf16(W1[idx[z]]^T)  [DFF][DD]   (clobbers Xhi/Xlo/Whi/Wlo: dead)
    transpose_cast<<<dim3(DFF / 32, DD / 32, BB), 256, 0, stream>>>(
        W1, IDX, W1T, DD, DFF, (long long)DD * DFF, (long long)DFF * DD);

    // H1bf = gelu(HSbf @ W1T^T + b1[e])  (bf16 out)
    gemm_bf16<1><<<dim3(DFF / 128, SS / 128, BB), 256, 0, stream>>>(
        HSbf, W1T, b1, H1bf, DFF, DD,
        (long long)SS * DD, (long long)SS * DFF, (long long)DFF * DD,
        nullptr, IDX);

    // W2T[z] = bf16(W2[idx[z]]^T)  [DD][DFF]   (clobbers W1T: dead)
    transpose_cast<<<dim3(DD / 32, DFF / 32, BB), 256, 0, stream>>>(
        W2, IDX, W2T, DFF, DD, (long long)DFF * DD, (long long)DD * DFF);

    // Ybf = (H1bf @ W2T^T + b2[e]) * w  (bf16 out)
    gemm_bf16<2><<<dim3(DD / 128, SS / 128, BB), 256, 0, stream>>>(
        H1bf, W2T, b2, Ybf, DD, DFF,
        (long long)SS * DFF, (long long)SS * DD, (long long)DD * DFF,
        WGATE, IDX);

    // Wfc -> bf16 (clobbers W2T + H1bf: dead)
    cast_kernel<<<4096, 256, 0, stream>>>(Wfc, Wfcbf, (long long)VOC * DD / 4);

    // logits = Ybf @ Wfcbf^T + bfc  (fp32 out)
    gemm_bf16<0><<<dim3(VOC / 128, (BB * SS) / 128, 1), 256, 0, stream>>>(
        Ybf, Wfcbf, bfc, out, VOC, DD, 0, 0, 0, nullptr, nullptr);
}